// Round 4
// baseline (622.399 us; speedup 1.0000x reference)
//
#include <hip/hip_runtime.h>
#include <math.h>

#define BATCH 64
#define CIN   256
#define HH    56
#define WW    56
#define HW    (HH*WW)      // 3136
#define WIDTH 64
#define COUT  256
#define K_CH  32
#define K_SP  1568
#define EPS   1e-5f
#define NCHUNK 13          // ceil(3136/256)

typedef short short8 __attribute__((ext_vector_type(8)));
typedef float f32x4 __attribute__((ext_vector_type(4)));

#define MFMA16(a, b, c) __builtin_amdgcn_mfma_f32_16x16x32_bf16((a), (b), (c), 0, 0, 0)

__device__ __forceinline__ unsigned short f2bf(float f) {
    unsigned u = __builtin_bit_cast(unsigned, f);
    u += 0x7fffu + ((u >> 16) & 1u);
    return (unsigned short)(u >> 16);
}

__device__ __forceinline__ double shflxor_f64(double v, int m) {
    union { double d; int i[2]; } u; u.d = v;
    u.i[0] = __shfl_xor(u.i[0], m, 64);
    u.i[1] = __shfl_xor(u.i[1], m, 64);
    return u.d;
}

// ---------------- Kernel 0: weight prep (fp32 -> bf16, conv2 -> [tap][oc][c]) ----------------
__global__ __launch_bounds__(256) void k_prep(const float* __restrict__ w1,
                                              const float* __restrict__ w2,
                                              const float* __restrict__ w3,
                                              short* __restrict__ w1bf,
                                              short* __restrict__ wt2,
                                              short* __restrict__ w3bf) {
    int i = blockIdx.x * 256 + threadIdx.x;
    if (i < 16384) {
        w1bf[i] = (short)f2bf(w1[i]);
    } else if (i < 53248) {
        int j = i - 16384;              // [tap][oc][c]
        int tap = j >> 12, rem = j & 4095;
        int oc = rem >> 6, c = rem & 63;
        wt2[j] = (short)f2bf(w2[oc * 576 + c * 9 + tap]);
    } else if (i < 69632) {
        int j = i - 53248;
        w3bf[j] = (short)f2bf(w3[j]);
    }
}

// ---------------- Kernel 1: FUSED single pass over x ----------------
// grid (NCHUNK, B), 256 thr. Per block: 256 px x all 256 c.
// Produces: spsal (f64), pooled_part (f64 per-chunk channel sums), xh (NHWC bf16).
__global__ __launch_bounds__(256) void k_fuse1(const float* __restrict__ x,
                                               const float* __restrict__ mask_w,
                                               const float* __restrict__ mask_b,
                                               double* __restrict__ spsal,
                                               double* __restrict__ pooled_part,
                                               short* __restrict__ xh) {
    __shared__ short tile[256][128];     // 64 KB, swizzled (8-short blocks)
    __shared__ double poolw[4][256];     // 8 KB
    __shared__ float wsh[256];
    int b = blockIdx.y, chunk = blockIdx.x;
    int px0 = chunk * 256;
    int tid = threadIdx.x;
    int w = tid >> 6;
    int px = px0 + tid;
    bool valid = px < HW;
    wsh[tid] = mask_w[tid];
    __syncthreads();
    double acc = 0.0;
    int swz = (tid & 7) << 3;
    for (int h = 0; h < 2; h++) {
#pragma unroll 4
        for (int cc = 0; cc < 128; cc++) {
            int c = h * 128 + cc;
            float v = valid ? x[((size_t)(b * 256 + c)) * HW + px] : 0.0f;
            acc += (double)v * (double)wsh[c];
            double s = (double)v;
            s += shflxor_f64(s, 1);
            s += shflxor_f64(s, 2);
            s += shflxor_f64(s, 4);
            s += shflxor_f64(s, 8);
            s += shflxor_f64(s, 16);
            s += shflxor_f64(s, 32);
            if ((tid & 63) == 0) poolw[w][c] = s;
            if (xh) tile[tid][cc ^ swz] = (short)f2bf(v);
        }
        __syncthreads();
        if (xh) {
#pragma unroll
            for (int it = 0; it < 16; it++) {
                int i = it * 256 + tid;
                int p = i >> 4, c8 = (i & 15) << 3;
                if (px0 + p < HW) {
                    short8 vv = *(const short8*)(&tile[p][c8 ^ ((p & 7) << 3)]);
                    *(short8*)(xh + ((size_t)(b * HW + px0 + p)) * 256 + h * 128 + c8) = vv;
                }
            }
        }
        __syncthreads();
    }
    if (valid) spsal[b * HW + px] = acc + (double)mask_b[0];
    // chunk-level channel partials (fixed order -> deterministic)
    pooled_part[((size_t)b * NCHUNK + chunk) * 256 + tid] =
        poolw[0][tid] + poolw[1][tid] + poolw[2][tid] + poolw[3][tid];
}

// ---------------- Kernel 3: channel saliency + top-K_CH mask ----------------
__global__ __launch_bounds__(64) void k_chan(const double* __restrict__ pooled_part,
                                             const float* __restrict__ fc_w,
                                             const float* __restrict__ fc_b,
                                             float* __restrict__ vector) {
    int b = blockIdx.x;
    int j = threadIdx.x;
    __shared__ double ps[CIN];
    for (int i = j; i < CIN; i += 64) {
        double s = 0.0;
        for (int k = 0; k < NCHUNK; k++) s += pooled_part[((size_t)b * NCHUNK + k) * 256 + i];
        ps[i] = s * (1.0 / (double)HW);
    }
    __syncthreads();
    double acc = (double)fc_b[j];
    const float* wr = fc_w + j * CIN;
    for (int k = 0; k < CIN; k++) acc += ps[k] * (double)wr[k];
    double sal = 1.0 / (1.0 + exp(-acc));
    __shared__ double ss[WIDTH];
    __shared__ double kth;
    ss[j] = sal;
    __syncthreads();
    int cg = 0, ce = 0;
    for (int i = 0; i < WIDTH; i++) {
        cg += (ss[i] > sal);
        ce += (ss[i] == sal);
    }
    if (cg <= K_CH - 1 && cg + ce >= K_CH) kth = sal;
    __syncthreads();
    vector[b * WIDTH + j] = (sal >= kth) ? 1.0f : 0.0f;
}

// ---------------- Kernel 4: spatial kth (bitonic select) + mask + 3x3 dilate ----------------
__global__ __launch_bounds__(1024) void k_spmask(const double* __restrict__ spsal,
                                                 float* __restrict__ mask,
                                                 float* __restrict__ mdil) {
    int b = blockIdx.x;
    int tid = threadIdx.x;
    __shared__ double s[4096];
    __shared__ float m[HW];
    for (int i = tid; i < 4096; i += 1024)
        s[i] = (i < HW) ? spsal[b * HW + i] : 1e300;
    __syncthreads();
    for (int k2 = 2; k2 <= 4096; k2 <<= 1) {
        for (int j2 = k2 >> 1; j2 > 0; j2 >>= 1) {
            for (int i = tid; i < 4096; i += 1024) {
                int ixj = i ^ j2;
                if (ixj > i) {
                    double a = s[i], c = s[ixj];
                    bool asc = ((i & k2) == 0);
                    bool swap = asc ? (a > c) : (a < c);
                    if (swap) { s[i] = c; s[ixj] = a; }
                }
            }
            __syncthreads();
        }
    }
    double kth = s[HW - K_SP];
    __syncthreads();
    for (int p = tid; p < HW; p += 1024) {
        float mv = (spsal[b * HW + p] >= kth) ? 1.0f : 0.0f;
        m[p] = mv;
        mask[b * HW + p] = mv;
    }
    __syncthreads();
    for (int p = tid; p < HW; p += 1024) {
        int y = p / WW, xx = p % WW;
        float mx = 0.0f;
        for (int dy = -1; dy <= 1; dy++) {
            int yy = y + dy;
            if (yy < 0 || yy >= HH) continue;
            for (int dx = -1; dx <= 1; dx++) {
                int xc = xx + dx;
                if (xc < 0 || xc >= WW) continue;
                mx = fmaxf(mx, m[yy * WW + xc]);
            }
        }
        mdil[b * HW + p] = mx;
    }
}

// ---------------- Kernel 5a: conv1 from NHWC xh (no LDS, streaming MFMA) ----------------
// grid (7, B), 256 thr = 4 waves; wave w: px = p0 + w*112 + ln + nt*16, all 64 oc.
__global__ __launch_bounds__(256, 2) void k_conv1n(const short* __restrict__ xh,
                                                   const short* __restrict__ w1bf,
                                                   const float* __restrict__ g1, const float* __restrict__ b1,
                                                   const float* __restrict__ m1, const float* __restrict__ v1,
                                                   const float* __restrict__ mdil,
                                                   const float* __restrict__ vec,
                                                   short* __restrict__ out1h) {
    int b = blockIdx.y, p0 = blockIdx.x * 448;
    int tid = threadIdx.x, w = tid >> 6, lane = tid & 63, g = lane >> 4, ln = lane & 15;
    int pxw = p0 + w * 112 + ln;
    f32x4 acc[4][7];
    f32x4 zz = {0.f, 0.f, 0.f, 0.f};
#pragma unroll
    for (int m = 0; m < 4; m++)
#pragma unroll
        for (int nt = 0; nt < 7; nt++) acc[m][nt] = zz;
#pragma unroll
    for (int ks = 0; ks < 8; ks++) {
        short8 afr[4];
#pragma unroll
        for (int m = 0; m < 4; m++)
            afr[m] = *(const short8*)(w1bf + (m * 16 + ln) * 256 + ks * 32 + g * 8);
#pragma unroll
        for (int nt = 0; nt < 7; nt++) {
            short8 bfr = *(const short8*)(xh + ((size_t)(b * HW) + pxw + nt * 16) * 256 + ks * 32 + g * 8);
#pragma unroll
            for (int m = 0; m < 4; m++) acc[m][nt] = MFMA16(afr[m], bfr, acc[m][nt]);
        }
    }
    // per-lane BN params (4 consecutive oc per lane)
    f32x4 sc4[4], sh4[4], vc4[4];
#pragma unroll
    for (int m = 0; m < 4; m++) {
        int oc = m * 16 + g * 4;
        f32x4 gg = *(const f32x4*)(g1 + oc);
        f32x4 bb = *(const f32x4*)(b1 + oc);
        f32x4 mm = *(const f32x4*)(m1 + oc);
        f32x4 vv = *(const f32x4*)(v1 + oc);
        f32x4 vcv = *(const f32x4*)(vec + b * 64 + oc);
#pragma unroll
        for (int i = 0; i < 4; i++) {
            sc4[m][i] = gg[i] * rsqrtf(vv[i] + EPS);
            sh4[m][i] = bb[i] - mm[i] * sc4[m][i];
        }
        vc4[m] = vcv;
    }
#pragma unroll
    for (int nt = 0; nt < 7; nt++) {
        int px = pxw + nt * 16;
        float md = mdil[b * HW + px];
#pragma unroll
        for (int m = 0; m < 4; m++) {
            float y0 = fmaxf(acc[m][nt][0] * sc4[m][0] + sh4[m][0], 0.f) * md * vc4[m][0];
            float y1 = fmaxf(acc[m][nt][1] * sc4[m][1] + sh4[m][1], 0.f) * md * vc4[m][1];
            float y2 = fmaxf(acc[m][nt][2] * sc4[m][2] + sh4[m][2], 0.f) * md * vc4[m][2];
            float y3 = fmaxf(acc[m][nt][3] * sc4[m][3] + sh4[m][3], 0.f) * md * vc4[m][3];
            uint2 u;
            u.x = (unsigned)f2bf(y0) | ((unsigned)f2bf(y1) << 16);
            u.y = (unsigned)f2bf(y2) | ((unsigned)f2bf(y3) << 16);
            *(uint2*)(out1h + ((size_t)(b * HW + px)) * 64 + m * 16 + g * 4) = u;
        }
    }
}

// ---------------- Kernel 5b: FALLBACK conv1 from NCHW x (LDS transpose) ----------------
__global__ __launch_bounds__(256, 2) void k_conv1fb(const float* __restrict__ x,
                                                    const short* __restrict__ w1bf,
                                                    const float* __restrict__ g1, const float* __restrict__ b1,
                                                    const float* __restrict__ m1, const float* __restrict__ v1,
                                                    const float* __restrict__ mdil,
                                                    const float* __restrict__ vec,
                                                    short* __restrict__ out1h) {
    __shared__ short lds[448 * 64];
    __shared__ float sc[64], sh[64], vs[64];
    int b = blockIdx.y, r0 = blockIdx.x * 8, p0 = r0 * 56;
    int tid = threadIdx.x, w = tid >> 6, lane = tid & 63, g = lane >> 4, ln = lane & 15;
    if (tid < 64) {
        float s = g1[tid] * rsqrtf(v1[tid] + EPS);
        sc[tid] = s; sh[tid] = b1[tid] - m1[tid] * s;
        vs[tid] = vec[b * 64 + tid];
    }
    f32x4 acc[4][7];
    f32x4 zz = {0.f, 0.f, 0.f, 0.f};
#pragma unroll
    for (int m = 0; m < 4; m++)
#pragma unroll
        for (int nt = 0; nt < 7; nt++) acc[m][nt] = zz;
    int pxl0 = w * 112 + ln;
    int swl = (pxl0 & 7) << 3;
    for (int kc = 0; kc < 4; kc++) {
        __syncthreads();
        const float* xsrc = x + ((size_t)(b * 256 + kc * 64)) * HW + p0;
        {
            int c = 0, px = tid;
            for (int i = 0; i < 112; i++) {
                float f = xsrc[(size_t)c * HW + px];
                lds[px * 64 + (c ^ ((px & 7) << 3))] = (short)f2bf(f);
                px += 256;
                if (px >= 448) { px -= 448; c++; }
            }
        }
        __syncthreads();
        short8 afr[4][2];
#pragma unroll
        for (int m = 0; m < 4; m++)
#pragma unroll
            for (int ks = 0; ks < 2; ks++)
                afr[m][ks] = *(const short8*)(w1bf + ((m * 16 + ln) * 256 + kc * 64 + ks * 32 + g * 8));
#pragma unroll
        for (int nt = 0; nt < 7; nt++) {
#pragma unroll
            for (int ks = 0; ks < 2; ks++) {
                short8 bfr = *(const short8*)(&lds[(pxl0 + nt * 16) * 64 + (((ks * 32 + g * 8)) ^ swl)]);
#pragma unroll
                for (int m = 0; m < 4; m++) acc[m][nt] = MFMA16(afr[m][ks], bfr, acc[m][nt]);
            }
        }
    }
#pragma unroll
    for (int nt = 0; nt < 7; nt++) {
        int px = p0 + pxl0 + nt * 16;
        float md = mdil[b * HW + px];
#pragma unroll
        for (int m = 0; m < 4; m++) {
            int oc = m * 16 + g * 4;
            float y0 = fmaxf(acc[m][nt][0] * sc[oc + 0] + sh[oc + 0], 0.f) * md * vs[oc + 0];
            float y1 = fmaxf(acc[m][nt][1] * sc[oc + 1] + sh[oc + 1], 0.f) * md * vs[oc + 1];
            float y2 = fmaxf(acc[m][nt][2] * sc[oc + 2] + sh[oc + 2], 0.f) * md * vs[oc + 2];
            float y3 = fmaxf(acc[m][nt][3] * sc[oc + 3] + sh[oc + 3], 0.f) * md * vs[oc + 3];
            uint2 u;
            u.x = (unsigned)f2bf(y0) | ((unsigned)f2bf(y1) << 16);
            u.y = (unsigned)f2bf(y2) | ((unsigned)f2bf(y3) << 16);
            *(uint2*)(out1h + ((size_t)(b * HW + px)) * 64 + m * 16 + g * 4) = u;
        }
    }
}

// ---------------- Kernel 6: conv2 3x3 (64->64) MFMA shift-GEMM + bn2 + relu + mask + vector ----------------
__global__ __launch_bounds__(256, 2) void k_conv2(const short* __restrict__ out1h,
                                                  const short* __restrict__ wt2,
                                                  const float* __restrict__ g2, const float* __restrict__ b2,
                                                  const float* __restrict__ m2, const float* __restrict__ v2,
                                                  const float* __restrict__ mask,
                                                  const float* __restrict__ vec,
                                                  short* __restrict__ out2h) {
    __shared__ short lds[10 * 58 * 64];
    __shared__ float sc[64], sh[64], vs[64];
    int b = blockIdx.y, r0 = blockIdx.x * 8, p0 = r0 * 56;
    int tid = threadIdx.x, w = tid >> 6, lane = tid & 63, g = lane >> 4, ln = lane & 15;
    if (tid < 64) {
        float s = g2[tid] * rsqrtf(v2[tid] + EPS);
        sc[tid] = s; sh[tid] = b2[tid] - m2[tid] * s;
        vs[tid] = vec[b * 64 + tid];
    }
    short8 z8 = {0, 0, 0, 0, 0, 0, 0, 0};
    for (int i = tid; i < 4640; i += 256) {
        int ri = i / 464, rem = i - ri * 464;
        int col = rem >> 3, c8 = (rem & 7) << 3;
        int gr = r0 - 1 + ri, gc = col - 1;
        short8 v8 = z8;
        if (gr >= 0 && gr < HH && gc >= 0 && gc < WW)
            v8 = *(const short8*)(out1h + ((size_t)(b * HW + gr * WW + gc)) * 64 + c8);
        *(short8*)(&lds[(ri * 58 + col) * 64 + (c8 ^ ((col & 7) << 3))]) = v8;
    }
    __syncthreads();

    f32x4 acc[4][7];
    f32x4 zz = {0.f, 0.f, 0.f, 0.f};
#pragma unroll
    for (int m = 0; m < 4; m++)
#pragma unroll
        for (int nt = 0; nt < 7; nt++) acc[m][nt] = zz;

    int prel0 = w * 112 + ln;
    for (int tap = 0; tap < 9; tap++) {
        int dy = tap / 3 - 1;
        int dx = tap - (tap / 3) * 3 - 1;
        short8 afr[4][2];
        const short* wt = wt2 + tap * 4096;
#pragma unroll
        for (int m = 0; m < 4; m++)
#pragma unroll
            for (int ks = 0; ks < 2; ks++)
                afr[m][ks] = *(const short8*)(wt + (m * 16 + ln) * 64 + ks * 32 + g * 8);
#pragma unroll
        for (int nt = 0; nt < 7; nt++) {
            int prel = prel0 + nt * 16;
            int rrel = prel / 56;
            int xcol = prel - rrel * 56;
            int row_l = rrel + 1 + dy;
            int col_l = xcol + 1 + dx;
            int base = (row_l * 58 + col_l) * 64;
            int sw = (col_l & 7) << 3;
#pragma unroll
            for (int ks = 0; ks < 2; ks++) {
                short8 bfr = *(const short8*)(&lds[base + ((ks * 32 + g * 8) ^ sw)]);
#pragma unroll
                for (int m = 0; m < 4; m++) acc[m][nt] = MFMA16(afr[m][ks], bfr, acc[m][nt]);
            }
        }
    }
#pragma unroll
    for (int nt = 0; nt < 7; nt++) {
        int px = p0 + prel0 + nt * 16;
        float mv = mask[b * HW + px];
#pragma unroll
        for (int m = 0; m < 4; m++) {
            int oc = m * 16 + g * 4;
            float y0 = fmaxf(acc[m][nt][0] * sc[oc + 0] + sh[oc + 0], 0.f) * mv * vs[oc + 0];
            float y1 = fmaxf(acc[m][nt][1] * sc[oc + 1] + sh[oc + 1], 0.f) * mv * vs[oc + 1];
            float y2 = fmaxf(acc[m][nt][2] * sc[oc + 2] + sh[oc + 2], 0.f) * mv * vs[oc + 2];
            float y3 = fmaxf(acc[m][nt][3] * sc[oc + 3] + sh[oc + 3], 0.f) * mv * vs[oc + 3];
            uint2 u;
            u.x = (unsigned)f2bf(y0) | ((unsigned)f2bf(y1) << 16);
            u.y = (unsigned)f2bf(y2) | ((unsigned)f2bf(y3) << 16);
            *(uint2*)(out2h + ((size_t)(b * HW + px)) * 64 + m * 16 + g * 4) = u;
        }
    }
}

// ---------------- Kernel 7: conv3 1x1 (64->256) swapped MFMA + x-prefetch + bn3 + mask + residual + relu ----------------
__global__ __launch_bounds__(256, 2) void k_conv3(const short* __restrict__ out2h,
                                                  const short* __restrict__ w3bf,
                                                  const float* __restrict__ g3, const float* __restrict__ b3,
                                                  const float* __restrict__ m3, const float* __restrict__ v3,
                                                  const float* __restrict__ mask,
                                                  const float* __restrict__ x,
                                                  float* __restrict__ out) {
    int b = blockIdx.y;
    int ocb = blockIdx.x / 28;          // 0..1
    int pxb = blockIdx.x % 28;          // 0..27
    int p0 = pxb * 112;
    int tid = threadIdx.x, w = tid >> 6, lane = tid & 63, g = lane >> 4, ln = lane & 15;
    int oc0 = ocb * 128 + w * 32;
    // prefetch residual x (14 x float4) FIRST for MLP
    f32x4 xr[2][7];
#pragma unroll
    for (int nt = 0; nt < 7; nt++) {
        int px0 = p0 + nt * 16 + g * 4;
#pragma unroll
        for (int m = 0; m < 2; m++) {
            int oc = oc0 + m * 16 + ln;
            xr[m][nt] = *(const f32x4*)(x + ((size_t)(b * COUT + oc)) * HW + px0);
        }
    }
    short8 wfr[2][2];
#pragma unroll
    for (int m = 0; m < 2; m++)
#pragma unroll
        for (int ks = 0; ks < 2; ks++)
            wfr[m][ks] = *(const short8*)(w3bf + ((oc0 + m * 16 + ln) * 64 + ks * 32 + g * 8));
    f32x4 acc[2][7];
    f32x4 zz = {0.f, 0.f, 0.f, 0.f};
#pragma unroll
    for (int m = 0; m < 2; m++)
#pragma unroll
        for (int nt = 0; nt < 7; nt++) acc[m][nt] = zz;
#pragma unroll
    for (int nt = 0; nt < 7; nt++) {
        size_t arow = ((size_t)(b * HW + p0 + nt * 16 + ln)) * 64;
#pragma unroll
        for (int ks = 0; ks < 2; ks++) {
            short8 act = *(const short8*)(out2h + arow + ks * 32 + g * 8);
#pragma unroll
            for (int m = 0; m < 2; m++) acc[m][nt] = MFMA16(act, wfr[m][ks], acc[m][nt]);
        }
    }
    // per-lane BN params (lane's oc fixed per m)
    float s_[2], h_[2];
#pragma unroll
    for (int m = 0; m < 2; m++) {
        int oc = oc0 + m * 16 + ln;
        float s = g3[oc] * rsqrtf(v3[oc] + EPS);
        s_[m] = s;
        h_[m] = b3[oc] - m3[oc] * s;
    }
#pragma unroll
    for (int nt = 0; nt < 7; nt++) {
        int px0 = p0 + nt * 16 + g * 4;
        f32x4 mv = *(const f32x4*)(mask + (size_t)b * HW + px0);
#pragma unroll
        for (int m = 0; m < 2; m++) {
            int oc = oc0 + m * 16 + ln;
            size_t idx = ((size_t)(b * COUT + oc)) * HW + px0;
            f32x4 o;
#pragma unroll
            for (int i = 0; i < 4; i++)
                o[i] = fmaxf(xr[m][nt][i] + (acc[m][nt][i] * s_[m] + h_[m]) * mv[i], 0.f);
            *(f32x4*)(out + idx) = o;
        }
    }
}

extern "C" void kernel_launch(void* const* d_in, const int* in_sizes, int n_in,
                              void* d_out, int out_size, void* d_ws, size_t ws_size,
                              hipStream_t stream) {
    const float* x       = (const float*)d_in[0];
    const float* conv1_w = (const float*)d_in[1];
    const float* bn1_g   = (const float*)d_in[2];
    const float* bn1_b   = (const float*)d_in[3];
    const float* bn1_m   = (const float*)d_in[4];
    const float* bn1_v   = (const float*)d_in[5];
    const float* conv2_w = (const float*)d_in[6];
    const float* bn2_g   = (const float*)d_in[7];
    const float* bn2_b   = (const float*)d_in[8];
    const float* bn2_m   = (const float*)d_in[9];
    const float* bn2_v   = (const float*)d_in[10];
    const float* conv3_w = (const float*)d_in[11];
    const float* bn3_g   = (const float*)d_in[12];
    const float* bn3_b   = (const float*)d_in[13];
    const float* bn3_m   = (const float*)d_in[14];
    const float* bn3_v   = (const float*)d_in[15];
    const float* fc_w    = (const float*)d_in[16];
    const float* fc_b    = (const float*)d_in[17];
    const float* mask_w  = (const float*)d_in[18];
    const float* mask_b  = (const float*)d_in[19];

    char* wsb = (char*)d_ws;
    size_t off = 0;
    double* pooled_part = (double*)(wsb + off); off += (size_t)BATCH * NCHUNK * 256 * 8;  // 1.70 MB
    double* spsal  = (double*)(wsb + off); off += (size_t)BATCH * HW * 8;                 // 1.61 MB
    float* vector  = (float*)(wsb + off);  off += (size_t)BATCH * WIDTH * 4;
    float* mask    = (float*)(wsb + off);  off += (size_t)BATCH * HW * 4;
    float* mdil    = (float*)(wsb + off);  off += (size_t)BATCH * HW * 4;
    short* w1bf    = (short*)(wsb + off);  off += (size_t)WIDTH * CIN * 2;
    short* wt2     = (short*)(wsb + off);  off += (size_t)9 * WIDTH * WIDTH * 2;
    short* w3bf    = (short*)(wsb + off);  off += (size_t)COUT * WIDTH * 2;
    short* out1h   = (short*)(wsb + off);  off += (size_t)BATCH * HW * WIDTH * 2;         // 25.7 MB
    size_t xh_off  = off;
    size_t xh_size = (size_t)BATCH * HW * CIN * 2;                                        // 102.8 MB
    size_t out2_size = (size_t)BATCH * HW * WIDTH * 2;
    bool use_xh = ws_size >= xh_off + xh_size;      // out2h aliases xh (xh dead before conv2)
    short* xh    = use_xh ? (short*)(wsb + xh_off) : (short*)nullptr;
    short* out2h = (short*)(wsb + xh_off);          // alias of xh (or own region in fallback)
    if (!use_xh) {
        // fallback layout: out2h right after out1h
        out2h = (short*)(wsb + xh_off);
        (void)out2_size;
    }
    (void)ws_size; (void)in_sizes; (void)n_in; (void)out_size;

    k_prep<<<272, 256, 0, stream>>>(conv1_w, conv2_w, conv3_w, w1bf, wt2, w3bf);
    k_fuse1<<<dim3(NCHUNK, BATCH), 256, 0, stream>>>(x, mask_w, mask_b, spsal, pooled_part, xh);
    k_chan<<<BATCH, 64, 0, stream>>>(pooled_part, fc_w, fc_b, vector);
    k_spmask<<<BATCH, 1024, 0, stream>>>(spsal, mask, mdil);
    if (use_xh)
        k_conv1n<<<dim3(7, BATCH), 256, 0, stream>>>(xh, w1bf, bn1_g, bn1_b, bn1_m, bn1_v, mdil, vector, out1h);
    else
        k_conv1fb<<<dim3(7, BATCH), 256, 0, stream>>>(x, w1bf, bn1_g, bn1_b, bn1_m, bn1_v, mdil, vector, out1h);
    k_conv2<<<dim3(7, BATCH), 256, 0, stream>>>(out1h, wt2, bn2_g, bn2_b, bn2_m, bn2_v, mask, vector, out2h);
    k_conv3<<<dim3(56, BATCH), 256, 0, stream>>>(out2h, w3bf, bn3_g, bn3_b, bn3_m, bn3_v, mask, x, (float*)d_out);
}

// Round 5
// 395.708 us; speedup vs baseline: 1.5729x; 1.5729x over previous
//
#include <hip/hip_runtime.h>
#include <math.h>

#define BATCH 64
#define CIN   256
#define HH    56
#define WW    56
#define HW    (HH*WW)      // 3136
#define WIDTH 64
#define COUT  256
#define K_CH  32
#define K_SP  1568
#define EPS   1e-5f

typedef short short8 __attribute__((ext_vector_type(8)));
typedef float f32x4 __attribute__((ext_vector_type(4)));

#define MFMA16(a, b, c) __builtin_amdgcn_mfma_f32_16x16x32_bf16((a), (b), (c), 0, 0, 0)

__device__ __forceinline__ unsigned short f2bf(float f) {
    unsigned u = __builtin_bit_cast(unsigned, f);
    u += 0x7fffu + ((u >> 16) & 1u);
    return (unsigned short)(u >> 16);
}

// ---------------- Kernel 0: weight prep (fp32 -> bf16, conv2 -> [tap][oc][c]) ----------------
__global__ __launch_bounds__(256) void k_prep(const float* __restrict__ w1,
                                              const float* __restrict__ w2,
                                              const float* __restrict__ w3,
                                              short* __restrict__ w1bf,
                                              short* __restrict__ wt2,
                                              short* __restrict__ w3bf) {
    int i = blockIdx.x * 256 + threadIdx.x;
    if (i < 16384) {
        w1bf[i] = (short)f2bf(w1[i]);
    } else if (i < 53248) {
        int j = i - 16384;              // [tap][oc][c]
        int tap = j >> 12, rem = j & 4095;
        int oc = rem >> 6, c = rem & 63;
        wt2[j] = (short)f2bf(w2[oc * 576 + c * 9 + tap]);
    } else if (i < 69632) {
        int j = i - 53248;
        w3bf[j] = (short)f2bf(w3[j]);
    }
}

// ---------------- Kernel 1: global average pool (double) ----------------
__global__ __launch_bounds__(256) void k_pool(const float* __restrict__ x, double* __restrict__ pooled) {
    int bc = blockIdx.x;
    const float* px = x + (size_t)bc * HW;
    double s = 0.0;
    for (int i = threadIdx.x; i < HW; i += 256) s += (double)px[i];
    __shared__ double red[256];
    red[threadIdx.x] = s;
    __syncthreads();
    for (int off = 128; off > 0; off >>= 1) {
        if (threadIdx.x < off) red[threadIdx.x] += red[threadIdx.x + off];
        __syncthreads();
    }
    if (threadIdx.x == 0) pooled[bc] = red[0] * (1.0 / (double)HW);
}

// ---------------- Kernel 2: spatial saliency 1x1 conv (double accum) ----------------
__global__ __launch_bounds__(256) void k_spsal(const float* __restrict__ x,
                                               const float* __restrict__ mask_w,
                                               const float* __restrict__ mask_b,
                                               double* __restrict__ spsal) {
    __shared__ float wsh[CIN];
    for (int i = threadIdx.x; i < CIN; i += 256) wsh[i] = mask_w[i];
    __syncthreads();
    int g = blockIdx.x * 256 + threadIdx.x;
    if (g >= BATCH * HW) return;
    int b = g / HW, p = g % HW;
    const float* px = x + (size_t)b * CIN * HW + p;
    double acc = 0.0;
#pragma unroll 8
    for (int c = 0; c < CIN; c++) acc += (double)px[(size_t)c * HW] * (double)wsh[c];
    spsal[g] = acc + (double)mask_b[0];
}

// ---------------- Kernel 3: channel saliency + top-K_CH mask ----------------
__global__ __launch_bounds__(64) void k_chan(const double* __restrict__ pooled,
                                             const float* __restrict__ fc_w,
                                             const float* __restrict__ fc_b,
                                             float* __restrict__ vector) {
    int b = blockIdx.x;
    int j = threadIdx.x;
    __shared__ double ps[CIN];
    for (int i = j; i < CIN; i += 64) ps[i] = pooled[b * CIN + i];
    __syncthreads();
    double acc = (double)fc_b[j];
    const float* wr = fc_w + j * CIN;
    for (int k = 0; k < CIN; k++) acc += ps[k] * (double)wr[k];
    double sal = 1.0 / (1.0 + exp(-acc));
    __shared__ double ss[WIDTH];
    __shared__ double kth;
    ss[j] = sal;
    __syncthreads();
    int cg = 0, ce = 0;
    for (int i = 0; i < WIDTH; i++) {
        cg += (ss[i] > sal);
        ce += (ss[i] == sal);
    }
    if (cg <= K_CH - 1 && cg + ce >= K_CH) kth = sal;
    __syncthreads();
    vector[b * WIDTH + j] = (sal >= kth) ? 1.0f : 0.0f;
}

// ---------------- Kernel 4: spatial kth (bitonic select) + mask + 3x3 dilate ----------------
__global__ __launch_bounds__(1024) void k_spmask(const double* __restrict__ spsal,
                                                 float* __restrict__ mask,
                                                 float* __restrict__ mdil) {
    int b = blockIdx.x;
    int tid = threadIdx.x;
    __shared__ double s[4096];
    __shared__ float m[HW];
    for (int i = tid; i < 4096; i += 1024)
        s[i] = (i < HW) ? spsal[b * HW + i] : 1e300;
    __syncthreads();
    for (int k2 = 2; k2 <= 4096; k2 <<= 1) {
        for (int j2 = k2 >> 1; j2 > 0; j2 >>= 1) {
            for (int i = tid; i < 4096; i += 1024) {
                int ixj = i ^ j2;
                if (ixj > i) {
                    double a = s[i], c = s[ixj];
                    bool asc = ((i & k2) == 0);
                    bool swap = asc ? (a > c) : (a < c);
                    if (swap) { s[i] = c; s[ixj] = a; }
                }
            }
            __syncthreads();
        }
    }
    double kth = s[HW - K_SP];
    __syncthreads();
    for (int p = tid; p < HW; p += 1024) {
        float mv = (spsal[b * HW + p] >= kth) ? 1.0f : 0.0f;
        m[p] = mv;
        mask[b * HW + p] = mv;
    }
    __syncthreads();
    for (int p = tid; p < HW; p += 1024) {
        int y = p / WW, xx = p % WW;
        float mx = 0.0f;
        for (int dy = -1; dy <= 1; dy++) {
            int yy = y + dy;
            if (yy < 0 || yy >= HH) continue;
            for (int dx = -1; dx <= 1; dx++) {
                int xc = xx + dx;
                if (xc < 0 || xc >= WW) continue;
                mx = fmaxf(mx, m[yy * WW + xc]);
            }
        }
        mdil[b * HW + p] = mx;
    }
}

// ---------------- Kernel 5: conv1 1x1 (256->64) MFMA + bn1 + relu + mdil + vector -> NHWC bf16 ----------------
__global__ __launch_bounds__(256, 2) void k_conv1(const float* __restrict__ x,
                                                  const short* __restrict__ w1bf,
                                                  const float* __restrict__ g1, const float* __restrict__ b1,
                                                  const float* __restrict__ m1, const float* __restrict__ v1,
                                                  const float* __restrict__ mdil,
                                                  const float* __restrict__ vec,
                                                  short* __restrict__ out1h) {
    __shared__ short lds[448 * 64];   // [px][c^swz], 57344 B
    __shared__ float sc[64], sh[64], vs[64];
    int b = blockIdx.y, r0 = blockIdx.x * 8, p0 = r0 * 56;
    int tid = threadIdx.x, w = tid >> 6, lane = tid & 63, g = lane >> 4, ln = lane & 15;
    if (tid < 64) {
        float s = g1[tid] * rsqrtf(v1[tid] + EPS);
        sc[tid] = s; sh[tid] = b1[tid] - m1[tid] * s;
        vs[tid] = vec[b * 64 + tid];
    }
    f32x4 acc[4][7];
    f32x4 zz = {0.f, 0.f, 0.f, 0.f};
#pragma unroll
    for (int m = 0; m < 4; m++)
#pragma unroll
        for (int nt = 0; nt < 7; nt++) acc[m][nt] = zz;

    int pxl0 = w * 112 + ln;
    int swl = (pxl0 & 7) << 3;

    for (int kc = 0; kc < 4; kc++) {
        __syncthreads();
        const float* xsrc = x + ((size_t)(b * 256 + kc * 64)) * HW + p0;
        {
            int c = 0, px = tid;
            for (int i = 0; i < 112; i++) {
                float f = xsrc[(size_t)c * HW + px];
                lds[px * 64 + (c ^ ((px & 7) << 3))] = (short)f2bf(f);
                px += 256;
                if (px >= 448) { px -= 448; c++; }
            }
        }
        __syncthreads();
        short8 afr[4][2];
#pragma unroll
        for (int m = 0; m < 4; m++)
#pragma unroll
            for (int ks = 0; ks < 2; ks++)
                afr[m][ks] = *(const short8*)(w1bf + ((m * 16 + ln) * 256 + kc * 64 + ks * 32 + g * 8));
#pragma unroll
        for (int nt = 0; nt < 7; nt++) {
#pragma unroll
            for (int ks = 0; ks < 2; ks++) {
                short8 bfr = *(const short8*)(&lds[(pxl0 + nt * 16) * 64 + (((ks * 32 + g * 8)) ^ swl)]);
#pragma unroll
                for (int m = 0; m < 4; m++) acc[m][nt] = MFMA16(afr[m][ks], bfr, acc[m][nt]);
            }
        }
    }
#pragma unroll
    for (int nt = 0; nt < 7; nt++) {
        int px = p0 + pxl0 + nt * 16;
        float md = mdil[b * HW + px];
#pragma unroll
        for (int m = 0; m < 4; m++) {
            unsigned pk0, pk1;
            {
                int oc = m * 16 + g * 4;
                float y0 = fmaxf(acc[m][nt][0] * sc[oc + 0] + sh[oc + 0], 0.f) * md * vs[oc + 0];
                float y1 = fmaxf(acc[m][nt][1] * sc[oc + 1] + sh[oc + 1], 0.f) * md * vs[oc + 1];
                float y2 = fmaxf(acc[m][nt][2] * sc[oc + 2] + sh[oc + 2], 0.f) * md * vs[oc + 2];
                float y3 = fmaxf(acc[m][nt][3] * sc[oc + 3] + sh[oc + 3], 0.f) * md * vs[oc + 3];
                pk0 = (unsigned)f2bf(y0) | ((unsigned)f2bf(y1) << 16);
                pk1 = (unsigned)f2bf(y2) | ((unsigned)f2bf(y3) << 16);
            }
            uint2 u; u.x = pk0; u.y = pk1;
            *(uint2*)(out1h + ((size_t)(b * HW + px)) * 64 + m * 16 + g * 4) = u;
        }
    }
}

// ---------------- Kernel 6: conv2 3x3 (64->64) MFMA shift-GEMM + bn2 + relu + mask + vector ----------------
__global__ __launch_bounds__(256, 2) void k_conv2(const short* __restrict__ out1h,
                                                  const short* __restrict__ wt2,
                                                  const float* __restrict__ g2, const float* __restrict__ b2,
                                                  const float* __restrict__ m2, const float* __restrict__ v2,
                                                  const float* __restrict__ mask,
                                                  const float* __restrict__ vec,
                                                  short* __restrict__ out2h) {
    __shared__ short lds[10 * 58 * 64];   // 74240 B
    __shared__ float sc[64], sh[64], vs[64];
    int b = blockIdx.y, r0 = blockIdx.x * 8, p0 = r0 * 56;
    int tid = threadIdx.x, w = tid >> 6, lane = tid & 63, g = lane >> 4, ln = lane & 15;
    if (tid < 64) {
        float s = g2[tid] * rsqrtf(v2[tid] + EPS);
        sc[tid] = s; sh[tid] = b2[tid] - m2[tid] * s;
        vs[tid] = vec[b * 64 + tid];
    }
    short8 z8 = {0, 0, 0, 0, 0, 0, 0, 0};
    for (int i = tid; i < 4640; i += 256) {
        int ri = i / 464, rem = i - ri * 464;
        int col = rem >> 3, c8 = (rem & 7) << 3;
        int gr = r0 - 1 + ri, gc = col - 1;
        short8 v8 = z8;
        if (gr >= 0 && gr < HH && gc >= 0 && gc < WW)
            v8 = *(const short8*)(out1h + ((size_t)(b * HW + gr * WW + gc)) * 64 + c8);
        *(short8*)(&lds[(ri * 58 + col) * 64 + (c8 ^ ((col & 7) << 3))]) = v8;
    }
    __syncthreads();

    f32x4 acc[4][7];
    f32x4 zz = {0.f, 0.f, 0.f, 0.f};
#pragma unroll
    for (int m = 0; m < 4; m++)
#pragma unroll
        for (int nt = 0; nt < 7; nt++) acc[m][nt] = zz;

    int prel0 = w * 112 + ln;
    for (int tap = 0; tap < 9; tap++) {
        int dy = tap / 3 - 1;
        int dx = tap - (tap / 3) * 3 - 1;
        short8 afr[4][2];
        const short* wt = wt2 + tap * 4096;
#pragma unroll
        for (int m = 0; m < 4; m++)
#pragma unroll
            for (int ks = 0; ks < 2; ks++)
                afr[m][ks] = *(const short8*)(wt + (m * 16 + ln) * 64 + ks * 32 + g * 8);
#pragma unroll
        for (int nt = 0; nt < 7; nt++) {
            int prel = prel0 + nt * 16;
            int rrel = prel / 56;
            int xcol = prel - rrel * 56;
            int row_l = rrel + 1 + dy;
            int col_l = xcol + 1 + dx;
            int base = (row_l * 58 + col_l) * 64;
            int sw = (col_l & 7) << 3;
#pragma unroll
            for (int ks = 0; ks < 2; ks++) {
                short8 bfr = *(const short8*)(&lds[base + ((ks * 32 + g * 8) ^ sw)]);
#pragma unroll
                for (int m = 0; m < 4; m++) acc[m][nt] = MFMA16(afr[m][ks], bfr, acc[m][nt]);
            }
        }
    }
#pragma unroll
    for (int nt = 0; nt < 7; nt++) {
        int px = p0 + prel0 + nt * 16;
        float mv = mask[b * HW + px];
#pragma unroll
        for (int m = 0; m < 4; m++) {
            int oc = m * 16 + g * 4;
            float y0 = fmaxf(acc[m][nt][0] * sc[oc + 0] + sh[oc + 0], 0.f) * mv * vs[oc + 0];
            float y1 = fmaxf(acc[m][nt][1] * sc[oc + 1] + sh[oc + 1], 0.f) * mv * vs[oc + 1];
            float y2 = fmaxf(acc[m][nt][2] * sc[oc + 2] + sh[oc + 2], 0.f) * mv * vs[oc + 2];
            float y3 = fmaxf(acc[m][nt][3] * sc[oc + 3] + sh[oc + 3], 0.f) * mv * vs[oc + 3];
            uint2 u;
            u.x = (unsigned)f2bf(y0) | ((unsigned)f2bf(y1) << 16);
            u.y = (unsigned)f2bf(y2) | ((unsigned)f2bf(y3) << 16);
            *(uint2*)(out2h + ((size_t)(b * HW + px)) * 64 + m * 16 + g * 4) = u;
        }
    }
}

// ---------------- Kernel 7: conv3 1x1 (64->256) swapped MFMA + x-prefetch + bn3 + mask + residual + relu ----------------
// grid (56, BATCH): blockIdx.x = ocb*28 + pxb; 256 thr = 4 waves; wave: 32 oc x 112 px.
// Swapped MFMA(A=act, B=weight) -> lane holds 4 CONSECUTIVE PIXELS per reg -> float4 x/mask/out.
__global__ __launch_bounds__(256, 2) void k_conv3(const short* __restrict__ out2h,
                                                  const short* __restrict__ w3bf,
                                                  const float* __restrict__ g3, const float* __restrict__ b3,
                                                  const float* __restrict__ m3, const float* __restrict__ v3,
                                                  const float* __restrict__ mask,
                                                  const float* __restrict__ x,
                                                  float* __restrict__ out) {
    int b = blockIdx.y;
    int ocb = blockIdx.x / 28;          // 0..1
    int pxb = blockIdx.x % 28;          // 0..27
    int p0 = pxb * 112;
    int tid = threadIdx.x, w = tid >> 6, lane = tid & 63, g = lane >> 4, ln = lane & 15;
    int oc0 = ocb * 128 + w * 32;
    // prefetch residual x (14 x float4) FIRST -> HBM latency overlaps act-load+MFMA phase
    f32x4 xr[2][7];
#pragma unroll
    for (int nt = 0; nt < 7; nt++) {
        int px0 = p0 + nt * 16 + g * 4;
#pragma unroll
        for (int m = 0; m < 2; m++) {
            int oc = oc0 + m * 16 + ln;
            xr[m][nt] = *(const f32x4*)(x + ((size_t)(b * COUT + oc)) * HW + px0);
        }
    }
    short8 wfr[2][2];
#pragma unroll
    for (int m = 0; m < 2; m++)
#pragma unroll
        for (int ks = 0; ks < 2; ks++)
            wfr[m][ks] = *(const short8*)(w3bf + ((oc0 + m * 16 + ln) * 64 + ks * 32 + g * 8));
    f32x4 acc[2][7];
    f32x4 zz = {0.f, 0.f, 0.f, 0.f};
#pragma unroll
    for (int m = 0; m < 2; m++)
#pragma unroll
        for (int nt = 0; nt < 7; nt++) acc[m][nt] = zz;
#pragma unroll
    for (int nt = 0; nt < 7; nt++) {
        size_t arow = ((size_t)(b * HW + p0 + nt * 16 + ln)) * 64;
#pragma unroll
        for (int ks = 0; ks < 2; ks++) {
            short8 act = *(const short8*)(out2h + arow + ks * 32 + g * 8);
#pragma unroll
            for (int m = 0; m < 2; m++) acc[m][nt] = MFMA16(act, wfr[m][ks], acc[m][nt]);
        }
    }
    // per-lane BN params (lane's oc fixed per m)
    float s_[2], h_[2];
#pragma unroll
    for (int m = 0; m < 2; m++) {
        int oc = oc0 + m * 16 + ln;
        float s = g3[oc] * rsqrtf(v3[oc] + EPS);
        s_[m] = s;
        h_[m] = b3[oc] - m3[oc] * s;
    }
#pragma unroll
    for (int nt = 0; nt < 7; nt++) {
        int px0 = p0 + nt * 16 + g * 4;
        f32x4 mv = *(const f32x4*)(mask + (size_t)b * HW + px0);
#pragma unroll
        for (int m = 0; m < 2; m++) {
            int oc = oc0 + m * 16 + ln;
            size_t idx = ((size_t)(b * COUT + oc)) * HW + px0;
            f32x4 o;
#pragma unroll
            for (int i = 0; i < 4; i++)
                o[i] = fmaxf(xr[m][nt][i] + (acc[m][nt][i] * s_[m] + h_[m]) * mv[i], 0.f);
            *(f32x4*)(out + idx) = o;
        }
    }
}

extern "C" void kernel_launch(void* const* d_in, const int* in_sizes, int n_in,
                              void* d_out, int out_size, void* d_ws, size_t ws_size,
                              hipStream_t stream) {
    const float* x       = (const float*)d_in[0];
    const float* conv1_w = (const float*)d_in[1];
    const float* bn1_g   = (const float*)d_in[2];
    const float* bn1_b   = (const float*)d_in[3];
    const float* bn1_m   = (const float*)d_in[4];
    const float* bn1_v   = (const float*)d_in[5];
    const float* conv2_w = (const float*)d_in[6];
    const float* bn2_g   = (const float*)d_in[7];
    const float* bn2_b   = (const float*)d_in[8];
    const float* bn2_m   = (const float*)d_in[9];
    const float* bn2_v   = (const float*)d_in[10];
    const float* conv3_w = (const float*)d_in[11];
    const float* bn3_g   = (const float*)d_in[12];
    const float* bn3_b   = (const float*)d_in[13];
    const float* bn3_m   = (const float*)d_in[14];
    const float* bn3_v   = (const float*)d_in[15];
    const float* fc_w    = (const float*)d_in[16];
    const float* fc_b    = (const float*)d_in[17];
    const float* mask_w  = (const float*)d_in[18];
    const float* mask_b  = (const float*)d_in[19];

    char* wsb = (char*)d_ws;
    size_t off = 0;
    double* pooled = (double*)(wsb + off); off += (size_t)BATCH * CIN * 8;
    double* spsal  = (double*)(wsb + off); off += (size_t)BATCH * HW * 8;
    float* vector  = (float*)(wsb + off);  off += (size_t)BATCH * WIDTH * 4;
    float* mask    = (float*)(wsb + off);  off += (size_t)BATCH * HW * 4;
    float* mdil    = (float*)(wsb + off);  off += (size_t)BATCH * HW * 4;
    short* w1bf    = (short*)(wsb + off);  off += (size_t)WIDTH * CIN * 2;
    short* wt2     = (short*)(wsb + off);  off += (size_t)9 * WIDTH * WIDTH * 2;
    short* w3bf    = (short*)(wsb + off);  off += (size_t)COUT * WIDTH * 2;
    short* out1h   = (short*)(wsb + off);  off += (size_t)BATCH * HW * WIDTH * 2;
    short* out2h   = (short*)(wsb + off);  off += (size_t)BATCH * HW * WIDTH * 2;
    (void)ws_size; (void)in_sizes; (void)n_in; (void)out_size;

    k_prep<<<272, 256, 0, stream>>>(conv1_w, conv2_w, conv3_w, w1bf, wt2, w3bf);
    k_pool<<<BATCH * CIN, 256, 0, stream>>>(x, pooled);
    k_spsal<<<(BATCH * HW + 255) / 256, 256, 0, stream>>>(x, mask_w, mask_b, spsal);
    k_chan<<<BATCH, 64, 0, stream>>>(pooled, fc_w, fc_b, vector);
    k_spmask<<<BATCH, 1024, 0, stream>>>(spsal, mask, mdil);
    k_conv1<<<dim3(7, BATCH), 256, 0, stream>>>(x, w1bf, bn1_g, bn1_b, bn1_m, bn1_v, mdil, vector, out1h);
    k_conv2<<<dim3(7, BATCH), 256, 0, stream>>>(out1h, wt2, bn2_g, bn2_b, bn2_m, bn2_v, mask, vector, out2h);
    k_conv3<<<dim3(56, BATCH), 256, 0, stream>>>(out2h, w3bf, bn3_g, bn3_b, bn3_m, bn3_v, mask, x, (float*)d_out);
}

// Round 6
// 387.662 us; speedup vs baseline: 1.6055x; 1.0208x over previous
//
#include <hip/hip_runtime.h>
#include <math.h>

#define BATCH 64
#define CIN   256
#define HH    56
#define WW    56
#define HW    (HH*WW)      // 3136
#define WIDTH 64
#define COUT  256
#define K_CH  32
#define K_SP  1568
#define EPS   1e-5f

typedef short short8 __attribute__((ext_vector_type(8)));
typedef float f32x4 __attribute__((ext_vector_type(4)));

#define MFMA16(a, b, c) __builtin_amdgcn_mfma_f32_16x16x32_bf16((a), (b), (c), 0, 0, 0)

__device__ __forceinline__ unsigned short f2bf(float f) {
    unsigned u = __builtin_bit_cast(unsigned, f);
    u += 0x7fffu + ((u >> 16) & 1u);
    return (unsigned short)(u >> 16);
}

// ---------------- Kernel 0: weight prep (fp32 -> bf16, conv2 -> [tap][oc][c]) ----------------
__global__ __launch_bounds__(256) void k_prep(const float* __restrict__ w1,
                                              const float* __restrict__ w2,
                                              const float* __restrict__ w3,
                                              short* __restrict__ w1bf,
                                              short* __restrict__ wt2,
                                              short* __restrict__ w3bf) {
    int i = blockIdx.x * 256 + threadIdx.x;
    if (i < 16384) {
        w1bf[i] = (short)f2bf(w1[i]);
    } else if (i < 53248) {
        int j = i - 16384;              // [tap][oc][c]
        int tap = j >> 12, rem = j & 4095;
        int oc = rem >> 6, c = rem & 63;
        wt2[j] = (short)f2bf(w2[oc * 576 + c * 9 + tap]);
    } else if (i < 69632) {
        int j = i - 53248;
        w3bf[j] = (short)f2bf(w3[j]);
    }
}

// ---------------- Kernel 1: global average pool (double) ----------------
__global__ __launch_bounds__(256) void k_pool(const float* __restrict__ x, double* __restrict__ pooled) {
    int bc = blockIdx.x;
    const float* px = x + (size_t)bc * HW;
    double s = 0.0;
    for (int i = threadIdx.x; i < HW; i += 256) s += (double)px[i];
    __shared__ double red[256];
    red[threadIdx.x] = s;
    __syncthreads();
    for (int off = 128; off > 0; off >>= 1) {
        if (threadIdx.x < off) red[threadIdx.x] += red[threadIdx.x + off];
        __syncthreads();
    }
    if (threadIdx.x == 0) pooled[bc] = red[0] * (1.0 / (double)HW);
}

// ---------------- Kernel 2: spatial saliency 1x1 conv (double accum) ----------------
__global__ __launch_bounds__(256) void k_spsal(const float* __restrict__ x,
                                               const float* __restrict__ mask_w,
                                               const float* __restrict__ mask_b,
                                               double* __restrict__ spsal) {
    __shared__ float wsh[CIN];
    for (int i = threadIdx.x; i < CIN; i += 256) wsh[i] = mask_w[i];
    __syncthreads();
    int g = blockIdx.x * 256 + threadIdx.x;
    if (g >= BATCH * HW) return;
    int b = g / HW, p = g % HW;
    const float* px = x + (size_t)b * CIN * HW + p;
    double acc = 0.0;
#pragma unroll 8
    for (int c = 0; c < CIN; c++) acc += (double)px[(size_t)c * HW] * (double)wsh[c];
    spsal[g] = acc + (double)mask_b[0];
}

// ---------------- Kernel 3: channel saliency + top-K_CH mask ----------------
__global__ __launch_bounds__(64) void k_chan(const double* __restrict__ pooled,
                                             const float* __restrict__ fc_w,
                                             const float* __restrict__ fc_b,
                                             float* __restrict__ vector) {
    int b = blockIdx.x;
    int j = threadIdx.x;
    __shared__ double ps[CIN];
    for (int i = j; i < CIN; i += 64) ps[i] = pooled[b * CIN + i];
    __syncthreads();
    double acc = (double)fc_b[j];
    const float* wr = fc_w + j * CIN;
    for (int k = 0; k < CIN; k++) acc += ps[k] * (double)wr[k];
    double sal = 1.0 / (1.0 + exp(-acc));
    __shared__ double ss[WIDTH];
    __shared__ double kth;
    ss[j] = sal;
    __syncthreads();
    int cg = 0, ce = 0;
    for (int i = 0; i < WIDTH; i++) {
        cg += (ss[i] > sal);
        ce += (ss[i] == sal);
    }
    if (cg <= K_CH - 1 && cg + ce >= K_CH) kth = sal;
    __syncthreads();
    vector[b * WIDTH + j] = (sal >= kth) ? 1.0f : 0.0f;
}

// ---------------- Kernel 4: spatial kth (bitonic select) + mask + 3x3 dilate ----------------
__global__ __launch_bounds__(1024) void k_spmask(const double* __restrict__ spsal,
                                                 float* __restrict__ mask,
                                                 float* __restrict__ mdil) {
    int b = blockIdx.x;
    int tid = threadIdx.x;
    __shared__ double s[4096];
    __shared__ float m[HW];
    for (int i = tid; i < 4096; i += 1024)
        s[i] = (i < HW) ? spsal[b * HW + i] : 1e300;
    __syncthreads();
    for (int k2 = 2; k2 <= 4096; k2 <<= 1) {
        for (int j2 = k2 >> 1; j2 > 0; j2 >>= 1) {
            for (int i = tid; i < 4096; i += 1024) {
                int ixj = i ^ j2;
                if (ixj > i) {
                    double a = s[i], c = s[ixj];
                    bool asc = ((i & k2) == 0);
                    bool swap = asc ? (a > c) : (a < c);
                    if (swap) { s[i] = c; s[ixj] = a; }
                }
            }
            __syncthreads();
        }
    }
    double kth = s[HW - K_SP];
    __syncthreads();
    for (int p = tid; p < HW; p += 1024) {
        float mv = (spsal[b * HW + p] >= kth) ? 1.0f : 0.0f;
        m[p] = mv;
        mask[b * HW + p] = mv;
    }
    __syncthreads();
    for (int p = tid; p < HW; p += 1024) {
        int y = p / WW, xx = p % WW;
        float mx = 0.0f;
        for (int dy = -1; dy <= 1; dy++) {
            int yy = y + dy;
            if (yy < 0 || yy >= HH) continue;
            for (int dx = -1; dx <= 1; dx++) {
                int xc = xx + dx;
                if (xc < 0 || xc >= WW) continue;
                mx = fmaxf(mx, m[yy * WW + xc]);
            }
        }
        mdil[b * HW + p] = mx;
    }
}

// ---------------- Kernel 5: conv1 1x1 (256->64) MFMA + bn1 + relu + mdil + vector -> NHWC bf16 ----------------
__global__ __launch_bounds__(256, 2) void k_conv1(const float* __restrict__ x,
                                                  const short* __restrict__ w1bf,
                                                  const float* __restrict__ g1, const float* __restrict__ b1,
                                                  const float* __restrict__ m1, const float* __restrict__ v1,
                                                  const float* __restrict__ mdil,
                                                  const float* __restrict__ vec,
                                                  short* __restrict__ out1h) {
    __shared__ short lds[448 * 64];   // [px][c^swz], 57344 B
    __shared__ float sc[64], sh[64], vs[64];
    int b = blockIdx.y, r0 = blockIdx.x * 8, p0 = r0 * 56;
    int tid = threadIdx.x, w = tid >> 6, lane = tid & 63, g = lane >> 4, ln = lane & 15;
    if (tid < 64) {
        float s = g1[tid] * rsqrtf(v1[tid] + EPS);
        sc[tid] = s; sh[tid] = b1[tid] - m1[tid] * s;
        vs[tid] = vec[b * 64 + tid];
    }
    f32x4 acc[4][7];
    f32x4 zz = {0.f, 0.f, 0.f, 0.f};
#pragma unroll
    for (int m = 0; m < 4; m++)
#pragma unroll
        for (int nt = 0; nt < 7; nt++) acc[m][nt] = zz;

    int pxl0 = w * 112 + ln;
    int swl = (pxl0 & 7) << 3;

    for (int kc = 0; kc < 4; kc++) {
        __syncthreads();
        const float* xsrc = x + ((size_t)(b * 256 + kc * 64)) * HW + p0;
        {
            int c = 0, px = tid;
            for (int i = 0; i < 112; i++) {
                float f = xsrc[(size_t)c * HW + px];
                lds[px * 64 + (c ^ ((px & 7) << 3))] = (short)f2bf(f);
                px += 256;
                if (px >= 448) { px -= 448; c++; }
            }
        }
        __syncthreads();
        short8 afr[4][2];
#pragma unroll
        for (int m = 0; m < 4; m++)
#pragma unroll
            for (int ks = 0; ks < 2; ks++)
                afr[m][ks] = *(const short8*)(w1bf + ((m * 16 + ln) * 256 + kc * 64 + ks * 32 + g * 8));
#pragma unroll
        for (int nt = 0; nt < 7; nt++) {
#pragma unroll
            for (int ks = 0; ks < 2; ks++) {
                short8 bfr = *(const short8*)(&lds[(pxl0 + nt * 16) * 64 + (((ks * 32 + g * 8)) ^ swl)]);
#pragma unroll
                for (int m = 0; m < 4; m++) acc[m][nt] = MFMA16(afr[m][ks], bfr, acc[m][nt]);
            }
        }
    }
#pragma unroll
    for (int nt = 0; nt < 7; nt++) {
        int px = p0 + pxl0 + nt * 16;
        float md = mdil[b * HW + px];
#pragma unroll
        for (int m = 0; m < 4; m++) {
            unsigned pk0, pk1;
            {
                int oc = m * 16 + g * 4;
                float y0 = fmaxf(acc[m][nt][0] * sc[oc + 0] + sh[oc + 0], 0.f) * md * vs[oc + 0];
                float y1 = fmaxf(acc[m][nt][1] * sc[oc + 1] + sh[oc + 1], 0.f) * md * vs[oc + 1];
                float y2 = fmaxf(acc[m][nt][2] * sc[oc + 2] + sh[oc + 2], 0.f) * md * vs[oc + 2];
                float y3 = fmaxf(acc[m][nt][3] * sc[oc + 3] + sh[oc + 3], 0.f) * md * vs[oc + 3];
                pk0 = (unsigned)f2bf(y0) | ((unsigned)f2bf(y1) << 16);
                pk1 = (unsigned)f2bf(y2) | ((unsigned)f2bf(y3) << 16);
            }
            uint2 u; u.x = pk0; u.y = pk1;
            *(uint2*)(out1h + ((size_t)(b * HW + px)) * 64 + m * 16 + g * 4) = u;
        }
    }
}

// ---------------- Kernel 6: conv2 3x3 (64->64) MFMA shift-GEMM + bn2 + relu + mask + vector ----------------
__global__ __launch_bounds__(256, 2) void k_conv2(const short* __restrict__ out1h,
                                                  const short* __restrict__ wt2,
                                                  const float* __restrict__ g2, const float* __restrict__ b2,
                                                  const float* __restrict__ m2, const float* __restrict__ v2,
                                                  const float* __restrict__ mask,
                                                  const float* __restrict__ vec,
                                                  short* __restrict__ out2h) {
    __shared__ short lds[10 * 58 * 64];   // 74240 B
    __shared__ float sc[64], sh[64], vs[64];
    int b = blockIdx.y, r0 = blockIdx.x * 8, p0 = r0 * 56;
    int tid = threadIdx.x, w = tid >> 6, lane = tid & 63, g = lane >> 4, ln = lane & 15;
    if (tid < 64) {
        float s = g2[tid] * rsqrtf(v2[tid] + EPS);
        sc[tid] = s; sh[tid] = b2[tid] - m2[tid] * s;
        vs[tid] = vec[b * 64 + tid];
    }
    short8 z8 = {0, 0, 0, 0, 0, 0, 0, 0};
    for (int i = tid; i < 4640; i += 256) {
        int ri = i / 464, rem = i - ri * 464;
        int col = rem >> 3, c8 = (rem & 7) << 3;
        int gr = r0 - 1 + ri, gc = col - 1;
        short8 v8 = z8;
        if (gr >= 0 && gr < HH && gc >= 0 && gc < WW)
            v8 = *(const short8*)(out1h + ((size_t)(b * HW + gr * WW + gc)) * 64 + c8);
        *(short8*)(&lds[(ri * 58 + col) * 64 + (c8 ^ ((col & 7) << 3))]) = v8;
    }
    __syncthreads();

    f32x4 acc[4][7];
    f32x4 zz = {0.f, 0.f, 0.f, 0.f};
#pragma unroll
    for (int m = 0; m < 4; m++)
#pragma unroll
        for (int nt = 0; nt < 7; nt++) acc[m][nt] = zz;

    int prel0 = w * 112 + ln;
    for (int tap = 0; tap < 9; tap++) {
        int dy = tap / 3 - 1;
        int dx = tap - (tap / 3) * 3 - 1;
        short8 afr[4][2];
        const short* wt = wt2 + tap * 4096;
#pragma unroll
        for (int m = 0; m < 4; m++)
#pragma unroll
            for (int ks = 0; ks < 2; ks++)
                afr[m][ks] = *(const short8*)(wt + (m * 16 + ln) * 64 + ks * 32 + g * 8);
#pragma unroll
        for (int nt = 0; nt < 7; nt++) {
            int prel = prel0 + nt * 16;
            int rrel = prel / 56;
            int xcol = prel - rrel * 56;
            int row_l = rrel + 1 + dy;
            int col_l = xcol + 1 + dx;
            int base = (row_l * 58 + col_l) * 64;
            int sw = (col_l & 7) << 3;
#pragma unroll
            for (int ks = 0; ks < 2; ks++) {
                short8 bfr = *(const short8*)(&lds[base + ((ks * 32 + g * 8) ^ sw)]);
#pragma unroll
                for (int m = 0; m < 4; m++) acc[m][nt] = MFMA16(afr[m][ks], bfr, acc[m][nt]);
            }
        }
    }
#pragma unroll
    for (int nt = 0; nt < 7; nt++) {
        int px = p0 + prel0 + nt * 16;
        float mv = mask[b * HW + px];
#pragma unroll
        for (int m = 0; m < 4; m++) {
            int oc = m * 16 + g * 4;
            float y0 = fmaxf(acc[m][nt][0] * sc[oc + 0] + sh[oc + 0], 0.f) * mv * vs[oc + 0];
            float y1 = fmaxf(acc[m][nt][1] * sc[oc + 1] + sh[oc + 1], 0.f) * mv * vs[oc + 1];
            float y2 = fmaxf(acc[m][nt][2] * sc[oc + 2] + sh[oc + 2], 0.f) * mv * vs[oc + 2];
            float y3 = fmaxf(acc[m][nt][3] * sc[oc + 3] + sh[oc + 3], 0.f) * mv * vs[oc + 3];
            uint2 u;
            u.x = (unsigned)f2bf(y0) | ((unsigned)f2bf(y1) << 16);
            u.y = (unsigned)f2bf(y2) | ((unsigned)f2bf(y3) << 16);
            *(uint2*)(out2h + ((size_t)(b * HW + px)) * 64 + m * 16 + g * 4) = u;
        }
    }
}

// ---------------- Kernel 7: conv3 1x1 (64->256) swapped MFMA, act-first + pinned x-prefetch ----------------
// grid (56, BATCH): blockIdx.x = ocb*28 + pxb; 256 thr = 4 waves; wave: 32 oc x 112 px.
// Order: act loads (oldest in vmcnt FIFO) -> x loads -> sched_barrier(0) -> MFMA (waits leave x
// in flight) -> epilogue vmcnt(0). VGPR ~200 expected — that's the prefetch staying alive.
__global__ __launch_bounds__(256, 2) void k_conv3(const short* __restrict__ out2h,
                                                  const short* __restrict__ w3bf,
                                                  const float* __restrict__ g3, const float* __restrict__ b3,
                                                  const float* __restrict__ m3, const float* __restrict__ v3,
                                                  const float* __restrict__ mask,
                                                  const float* __restrict__ x,
                                                  float* __restrict__ out) {
    int b = blockIdx.y;
    int ocb = blockIdx.x / 28;          // 0..1
    int pxb = blockIdx.x % 28;          // 0..27
    int p0 = pxb * 112;
    int tid = threadIdx.x, w = tid >> 6, lane = tid & 63, g = lane >> 4, ln = lane & 15;
    int oc0 = ocb * 128 + w * 32;

    // (1) weight fragments
    short8 wfr[2][2];
#pragma unroll
    for (int m = 0; m < 2; m++)
#pragma unroll
        for (int ks = 0; ks < 2; ks++)
            wfr[m][ks] = *(const short8*)(w3bf + ((oc0 + m * 16 + ln) * 64 + ks * 32 + g * 8));

    // (2) act loads FIRST (MFMA waits on these -> oldest in FIFO)
    short8 act[7][2];
#pragma unroll
    for (int nt = 0; nt < 7; nt++) {
        size_t arow = ((size_t)(b * HW + p0 + nt * 16 + ln)) * 64;
#pragma unroll
        for (int ks = 0; ks < 2; ks++)
            act[nt][ks] = *(const short8*)(out2h + arow + ks * 32 + g * 8);
    }

    // (3) residual x prefetch SECOND (stays outstanding through the MFMA phase)
    f32x4 xr[2][7];
#pragma unroll
    for (int nt = 0; nt < 7; nt++) {
        int px0 = p0 + nt * 16 + g * 4;
#pragma unroll
        for (int m = 0; m < 2; m++) {
            int oc = oc0 + m * 16 + ln;
            xr[m][nt] = *(const f32x4*)(x + ((size_t)(b * COUT + oc)) * HW + px0);
        }
    }
    __builtin_amdgcn_sched_barrier(0);   // pin: no sinking of the prefetch past this point

    // (4) MFMA phase
    f32x4 acc[2][7];
    f32x4 zz = {0.f, 0.f, 0.f, 0.f};
#pragma unroll
    for (int m = 0; m < 2; m++)
#pragma unroll
        for (int nt = 0; nt < 7; nt++) acc[m][nt] = zz;
#pragma unroll
    for (int nt = 0; nt < 7; nt++)
#pragma unroll
        for (int ks = 0; ks < 2; ks++)
#pragma unroll
            for (int m = 0; m < 2; m++)
                acc[m][nt] = MFMA16(act[nt][ks], wfr[m][ks], acc[m][nt]);

    // (5) epilogue: per-lane BN, mask, residual add, relu, float4 stores
    float s_[2], h_[2];
#pragma unroll
    for (int m = 0; m < 2; m++) {
        int oc = oc0 + m * 16 + ln;
        float s = g3[oc] * rsqrtf(v3[oc] + EPS);
        s_[m] = s;
        h_[m] = b3[oc] - m3[oc] * s;
    }
#pragma unroll
    for (int nt = 0; nt < 7; nt++) {
        int px0 = p0 + nt * 16 + g * 4;
        f32x4 mv = *(const f32x4*)(mask + (size_t)b * HW + px0);
#pragma unroll
        for (int m = 0; m < 2; m++) {
            int oc = oc0 + m * 16 + ln;
            size_t idx = ((size_t)(b * COUT + oc)) * HW + px0;
            f32x4 o;
#pragma unroll
            for (int i = 0; i < 4; i++)
                o[i] = fmaxf(xr[m][nt][i] + (acc[m][nt][i] * s_[m] + h_[m]) * mv[i], 0.f);
            *(f32x4*)(out + idx) = o;
        }
    }
}

extern "C" void kernel_launch(void* const* d_in, const int* in_sizes, int n_in,
                              void* d_out, int out_size, void* d_ws, size_t ws_size,
                              hipStream_t stream) {
    const float* x       = (const float*)d_in[0];
    const float* conv1_w = (const float*)d_in[1];
    const float* bn1_g   = (const float*)d_in[2];
    const float* bn1_b   = (const float*)d_in[3];
    const float* bn1_m   = (const float*)d_in[4];
    const float* bn1_v   = (const float*)d_in[5];
    const float* conv2_w = (const float*)d_in[6];
    const float* bn2_g   = (const float*)d_in[7];
    const float* bn2_b   = (const float*)d_in[8];
    const float* bn2_m   = (const float*)d_in[9];
    const float* bn2_v   = (const float*)d_in[10];
    const float* conv3_w = (const float*)d_in[11];
    const float* bn3_g   = (const float*)d_in[12];
    const float* bn3_b   = (const float*)d_in[13];
    const float* bn3_m   = (const float*)d_in[14];
    const float* bn3_v   = (const float*)d_in[15];
    const float* fc_w    = (const float*)d_in[16];
    const float* fc_b    = (const float*)d_in[17];
    const float* mask_w  = (const float*)d_in[18];
    const float* mask_b  = (const float*)d_in[19];

    char* wsb = (char*)d_ws;
    size_t off = 0;
    double* pooled = (double*)(wsb + off); off += (size_t)BATCH * CIN * 8;
    double* spsal  = (double*)(wsb + off); off += (size_t)BATCH * HW * 8;
    float* vector  = (float*)(wsb + off);  off += (size_t)BATCH * WIDTH * 4;
    float* mask    = (float*)(wsb + off);  off += (size_t)BATCH * HW * 4;
    float* mdil    = (float*)(wsb + off);  off += (size_t)BATCH * HW * 4;
    short* w1bf    = (short*)(wsb + off);  off += (size_t)WIDTH * CIN * 2;
    short* wt2     = (short*)(wsb + off);  off += (size_t)9 * WIDTH * WIDTH * 2;
    short* w3bf    = (short*)(wsb + off);  off += (size_t)COUT * WIDTH * 2;
    short* out1h   = (short*)(wsb + off);  off += (size_t)BATCH * HW * WIDTH * 2;
    short* out2h   = (short*)(wsb + off);  off += (size_t)BATCH * HW * WIDTH * 2;
    (void)ws_size; (void)in_sizes; (void)n_in; (void)out_size;

    k_prep<<<272, 256, 0, stream>>>(conv1_w, conv2_w, conv3_w, w1bf, wt2, w3bf);
    k_pool<<<BATCH * CIN, 256, 0, stream>>>(x, pooled);
    k_spsal<<<(BATCH * HW + 255) / 256, 256, 0, stream>>>(x, mask_w, mask_b, spsal);
    k_chan<<<BATCH, 64, 0, stream>>>(pooled, fc_w, fc_b, vector);
    k_spmask<<<BATCH, 1024, 0, stream>>>(spsal, mask, mdil);
    k_conv1<<<dim3(7, BATCH), 256, 0, stream>>>(x, w1bf, bn1_g, bn1_b, bn1_m, bn1_v, mdil, vector, out1h);
    k_conv2<<<dim3(7, BATCH), 256, 0, stream>>>(out1h, wt2, bn2_g, bn2_b, bn2_m, bn2_v, mask, vector, out2h);
    k_conv3<<<dim3(56, BATCH), 256, 0, stream>>>(out2h, w3bf, bn3_g, bn3_b, bn3_m, bn3_v, mask, x, (float*)d_out);
}

// Round 7
// 323.858 us; speedup vs baseline: 1.9218x; 1.1970x over previous
//
#include <hip/hip_runtime.h>
#include <math.h>

#define BATCH 64
#define CIN   256
#define HH    56
#define WW    56
#define HW    (HH*WW)      // 3136
#define WIDTH 64
#define COUT  256
#define K_CH  32
#define K_SP  1568
#define EPS   1e-5f

typedef short short8 __attribute__((ext_vector_type(8)));
typedef float f32x4 __attribute__((ext_vector_type(4)));

#define MFMA16(a, b, c) __builtin_amdgcn_mfma_f32_16x16x32_bf16((a), (b), (c), 0, 0, 0)

__device__ __forceinline__ unsigned short f2bf(float f) {
    unsigned u = __builtin_bit_cast(unsigned, f);
    u += 0x7fffu + ((u >> 16) & 1u);
    return (unsigned short)(u >> 16);
}

// ---------------- Kernel 0: weight prep (fp32 -> bf16, conv2 -> [tap][oc][c]) ----------------
__global__ __launch_bounds__(256) void k_prep(const float* __restrict__ w1,
                                              const float* __restrict__ w2,
                                              const float* __restrict__ w3,
                                              short* __restrict__ w1bf,
                                              short* __restrict__ wt2,
                                              short* __restrict__ w3bf) {
    int i = blockIdx.x * 256 + threadIdx.x;
    if (i < 16384) {
        w1bf[i] = (short)f2bf(w1[i]);
    } else if (i < 53248) {
        int j = i - 16384;              // [tap][oc][c]
        int tap = j >> 12, rem = j & 4095;
        int oc = rem >> 6, c = rem & 63;
        wt2[j] = (short)f2bf(w2[oc * 576 + c * 9 + tap]);
    } else if (i < 69632) {
        int j = i - 53248;
        w3bf[j] = (short)f2bf(w3[j]);
    }
}

// ---------------- Kernel 1: FUSED pool + spatial-saliency, single x pass ----------------
// grid (16, BATCH), 256 thr. Block = (b, 16-channel tile). Thread = pixel column (13 slots).
// Per element: 1 f64 FMA (spsal partial, register) + 1 f64 add (channel sum, register).
// No cross-lane f64 shuffles, no transposed LDS staging (round-4 lesson).
__global__ __launch_bounds__(256) void k_poolsal(const float* __restrict__ x,
                                                 const float* __restrict__ mask_w,
                                                 double* __restrict__ pooled,
                                                 double* __restrict__ spart) {
    int ct = blockIdx.x, b = blockIdx.y;
    int tid = threadIdx.x;
    double sp[13];
#pragma unroll
    for (int i = 0; i < 13; i++) sp[i] = 0.0;
    double pc[16];
#pragma unroll
    for (int c = 0; c < 16; c++) pc[c] = 0.0;

#pragma unroll
    for (int c = 0; c < 16; c++) {
        const float* xr = x + ((size_t)(b * CIN + ct * 16 + c)) * HW;
        double w = (double)mask_w[ct * 16 + c];
#pragma unroll
        for (int i = 0; i < 13; i++) {
            int px = i * 256 + tid;
            if (px < HW) {
                double v = (double)xr[px];
                sp[i] += v * w;
                pc[c] += v;
            }
        }
    }
    // spatial partials out (summed in fixed ct-order by k_spmask)
    double* so = spart + ((size_t)(b * 16 + ct)) * HW;
#pragma unroll
    for (int i = 0; i < 13; i++) {
        int px = i * 256 + tid;
        if (px < HW) so[px] = sp[i];
    }
    // channel sums: complete within this block (all pixels) -> reduce 256 lanes via LDS tree
    __shared__ double pl[16][257];
#pragma unroll
    for (int c = 0; c < 16; c++) pl[c][tid] = pc[c];
    __syncthreads();
    for (int off = 128; off > 0; off >>= 1) {
        for (int k = tid; k < 16 * off; k += 256) {
            int c = k / off, j = k - c * off;
            pl[c][j] += pl[c][j + off];
        }
        __syncthreads();
    }
    if (tid < 16) pooled[b * CIN + ct * 16 + tid] = pl[tid][0] * (1.0 / (double)HW);
}

// ---------------- Kernel 3: channel saliency + top-K_CH mask ----------------
__global__ __launch_bounds__(64) void k_chan(const double* __restrict__ pooled,
                                             const float* __restrict__ fc_w,
                                             const float* __restrict__ fc_b,
                                             float* __restrict__ vector) {
    int b = blockIdx.x;
    int j = threadIdx.x;
    __shared__ double ps[CIN];
    for (int i = j; i < CIN; i += 64) ps[i] = pooled[b * CIN + i];
    __syncthreads();
    double acc = (double)fc_b[j];
    const float* wr = fc_w + j * CIN;
    for (int k = 0; k < CIN; k++) acc += ps[k] * (double)wr[k];
    double sal = 1.0 / (1.0 + exp(-acc));
    __shared__ double ss[WIDTH];
    __shared__ double kth;
    ss[j] = sal;
    __syncthreads();
    int cg = 0, ce = 0;
    for (int i = 0; i < WIDTH; i++) {
        cg += (ss[i] > sal);
        ce += (ss[i] == sal);
    }
    if (cg <= K_CH - 1 && cg + ce >= K_CH) kth = sal;
    __syncthreads();
    vector[b * WIDTH + j] = (sal >= kth) ? 1.0f : 0.0f;
}

// ---------------- Kernel 4: spatial kth via EXACT 64-bit radix-select + mask + 3x3 dilate ----------------
// grid (BATCH), 256 thr. Sums the 16 f64 partials per pixel (fixed order), maps f64 -> order-
// preserving u64 key, then 8 passes of 8-bit MSB radix-select resolve the kth-largest key exactly.
// mask = (key >= kth_key) — bit-identical to sorting the f64s.
__global__ __launch_bounds__(256) void k_spmask(const double* __restrict__ spart,
                                                float* __restrict__ mask,
                                                float* __restrict__ mdil) {
    int b = blockIdx.x;
    int tid = threadIdx.x;
    __shared__ unsigned long long ks[HW];    // 25 KB
    __shared__ float m[HW];                  // 12.5 KB
    __shared__ unsigned int hist[256];
    __shared__ unsigned int sc[256];
    __shared__ unsigned long long sh_prefix;
    __shared__ unsigned int sh_krem;

    // build keys (fixed-order partial sum over the 16 channel tiles)
#pragma unroll
    for (int i = 0; i < 13; i++) {
        int px = i * 256 + tid;
        if (px < HW) {
            double s = 0.0;
#pragma unroll
            for (int t = 0; t < 16; t++) s += spart[((size_t)(b * 16 + t)) * HW + px];
            unsigned long long u = __builtin_bit_cast(unsigned long long, s);
            ks[px] = (u >> 63) ? ~u : (u | 0x8000000000000000ULL);
        }
    }
    if (tid == 0) { sh_prefix = 0ULL; sh_krem = K_SP; }
    __syncthreads();

    unsigned long long pmask = 0ULL;
    for (int pass = 0; pass < 8; pass++) {
        int shift = 56 - 8 * pass;
        hist[tid] = 0;
        __syncthreads();
        unsigned long long prefix = sh_prefix;
#pragma unroll
        for (int i = 0; i < 13; i++) {
            int px = i * 256 + tid;
            if (px < HW) {
                unsigned long long k = ks[px];
                if ((k & pmask) == prefix)
                    atomicAdd(&hist[(unsigned)((k >> shift) & 255ULL)], 1u);
            }
        }
        __syncthreads();
        // sc[i] = sum over top i+1 digits: sc[i] = sum_{j<=i} hist[255-j]
        sc[tid] = hist[255 - tid];
        __syncthreads();
        for (int off = 1; off < 256; off <<= 1) {
            unsigned v = sc[tid];
            unsigned a = (tid >= off) ? sc[tid - off] : 0u;
            __syncthreads();
            sc[tid] = v + a;
            __syncthreads();
        }
        unsigned krem = sh_krem;
        unsigned cum = sc[tid];                         // digits >= d, d = 255 - tid
        unsigned cumHigher = (tid > 0) ? sc[tid - 1] : 0u;  // digits > d
        __syncthreads();
        if (cum >= krem && cumHigher < krem) {          // exactly one winner
            int d = 255 - tid;
            sh_krem = krem - cumHigher;
            sh_prefix = prefix | ((unsigned long long)d << shift);
        }
        pmask |= (0xFFULL << shift);
        __syncthreads();
    }
    unsigned long long kth = sh_prefix;

#pragma unroll
    for (int i = 0; i < 13; i++) {
        int px = i * 256 + tid;
        if (px < HW) {
            float mv = (ks[px] >= kth) ? 1.0f : 0.0f;
            m[px] = mv;
            mask[b * HW + px] = mv;
        }
    }
    __syncthreads();
    for (int p = tid; p < HW; p += 256) {
        int y = p / WW, xx = p % WW;
        float mx = 0.0f;
        for (int dy = -1; dy <= 1; dy++) {
            int yy = y + dy;
            if (yy < 0 || yy >= HH) continue;
            for (int dx = -1; dx <= 1; dx++) {
                int xc = xx + dx;
                if (xc < 0 || xc >= WW) continue;
                mx = fmaxf(mx, m[yy * WW + xc]);
            }
        }
        mdil[b * HW + p] = mx;
    }
}

// ---------------- Kernel 5: conv1 1x1 (256->64) MFMA + bn1 + relu + mdil + vector -> NHWC bf16 ----------------
__global__ __launch_bounds__(256, 2) void k_conv1(const float* __restrict__ x,
                                                  const short* __restrict__ w1bf,
                                                  const float* __restrict__ g1, const float* __restrict__ b1,
                                                  const float* __restrict__ m1, const float* __restrict__ v1,
                                                  const float* __restrict__ mdil,
                                                  const float* __restrict__ vec,
                                                  short* __restrict__ out1h) {
    __shared__ short lds[448 * 64];   // [px][c^swz], 57344 B
    __shared__ float sc[64], sh[64], vs[64];
    int b = blockIdx.y, r0 = blockIdx.x * 8, p0 = r0 * 56;
    int tid = threadIdx.x, w = tid >> 6, lane = tid & 63, g = lane >> 4, ln = lane & 15;
    if (tid < 64) {
        float s = g1[tid] * rsqrtf(v1[tid] + EPS);
        sc[tid] = s; sh[tid] = b1[tid] - m1[tid] * s;
        vs[tid] = vec[b * 64 + tid];
    }
    f32x4 acc[4][7];
    f32x4 zz = {0.f, 0.f, 0.f, 0.f};
#pragma unroll
    for (int m = 0; m < 4; m++)
#pragma unroll
        for (int nt = 0; nt < 7; nt++) acc[m][nt] = zz;

    int pxl0 = w * 112 + ln;
    int swl = (pxl0 & 7) << 3;

    for (int kc = 0; kc < 4; kc++) {
        __syncthreads();
        const float* xsrc = x + ((size_t)(b * 256 + kc * 64)) * HW + p0;
        {
            int c = 0, px = tid;
            for (int i = 0; i < 112; i++) {
                float f = xsrc[(size_t)c * HW + px];
                lds[px * 64 + (c ^ ((px & 7) << 3))] = (short)f2bf(f);
                px += 256;
                if (px >= 448) { px -= 448; c++; }
            }
        }
        __syncthreads();
        short8 afr[4][2];
#pragma unroll
        for (int m = 0; m < 4; m++)
#pragma unroll
            for (int ks = 0; ks < 2; ks++)
                afr[m][ks] = *(const short8*)(w1bf + ((m * 16 + ln) * 256 + kc * 64 + ks * 32 + g * 8));
#pragma unroll
        for (int nt = 0; nt < 7; nt++) {
#pragma unroll
            for (int ks = 0; ks < 2; ks++) {
                short8 bfr = *(const short8*)(&lds[(pxl0 + nt * 16) * 64 + (((ks * 32 + g * 8)) ^ swl)]);
#pragma unroll
                for (int m = 0; m < 4; m++) acc[m][nt] = MFMA16(afr[m][ks], bfr, acc[m][nt]);
            }
        }
    }
#pragma unroll
    for (int nt = 0; nt < 7; nt++) {
        int px = p0 + pxl0 + nt * 16;
        float md = mdil[b * HW + px];
#pragma unroll
        for (int m = 0; m < 4; m++) {
            unsigned pk0, pk1;
            {
                int oc = m * 16 + g * 4;
                float y0 = fmaxf(acc[m][nt][0] * sc[oc + 0] + sh[oc + 0], 0.f) * md * vs[oc + 0];
                float y1 = fmaxf(acc[m][nt][1] * sc[oc + 1] + sh[oc + 1], 0.f) * md * vs[oc + 1];
                float y2 = fmaxf(acc[m][nt][2] * sc[oc + 2] + sh[oc + 2], 0.f) * md * vs[oc + 2];
                float y3 = fmaxf(acc[m][nt][3] * sc[oc + 3] + sh[oc + 3], 0.f) * md * vs[oc + 3];
                pk0 = (unsigned)f2bf(y0) | ((unsigned)f2bf(y1) << 16);
                pk1 = (unsigned)f2bf(y2) | ((unsigned)f2bf(y3) << 16);
            }
            uint2 u; u.x = pk0; u.y = pk1;
            *(uint2*)(out1h + ((size_t)(b * HW + px)) * 64 + m * 16 + g * 4) = u;
        }
    }
}

// ---------------- Kernel 6: conv2 3x3 (64->64) MFMA shift-GEMM + bn2 + relu + mask + vector ----------------
__global__ __launch_bounds__(256, 2) void k_conv2(const short* __restrict__ out1h,
                                                  const short* __restrict__ wt2,
                                                  const float* __restrict__ g2, const float* __restrict__ b2,
                                                  const float* __restrict__ m2, const float* __restrict__ v2,
                                                  const float* __restrict__ mask,
                                                  const float* __restrict__ vec,
                                                  short* __restrict__ out2h) {
    __shared__ short lds[10 * 58 * 64];   // 74240 B
    __shared__ float sc[64], sh[64], vs[64];
    int b = blockIdx.y, r0 = blockIdx.x * 8, p0 = r0 * 56;
    int tid = threadIdx.x, w = tid >> 6, lane = tid & 63, g = lane >> 4, ln = lane & 15;
    if (tid < 64) {
        float s = g2[tid] * rsqrtf(v2[tid] + EPS);
        sc[tid] = s; sh[tid] = b2[tid] - m2[tid] * s;
        vs[tid] = vec[b * 64 + tid];
    }
    short8 z8 = {0, 0, 0, 0, 0, 0, 0, 0};
    for (int i = tid; i < 4640; i += 256) {
        int ri = i / 464, rem = i - ri * 464;
        int col = rem >> 3, c8 = (rem & 7) << 3;
        int gr = r0 - 1 + ri, gc = col - 1;
        short8 v8 = z8;
        if (gr >= 0 && gr < HH && gc >= 0 && gc < WW)
            v8 = *(const short8*)(out1h + ((size_t)(b * HW + gr * WW + gc)) * 64 + c8);
        *(short8*)(&lds[(ri * 58 + col) * 64 + (c8 ^ ((col & 7) << 3))]) = v8;
    }
    __syncthreads();

    f32x4 acc[4][7];
    f32x4 zz = {0.f, 0.f, 0.f, 0.f};
#pragma unroll
    for (int m = 0; m < 4; m++)
#pragma unroll
        for (int nt = 0; nt < 7; nt++) acc[m][nt] = zz;

    int prel0 = w * 112 + ln;
    for (int tap = 0; tap < 9; tap++) {
        int dy = tap / 3 - 1;
        int dx = tap - (tap / 3) * 3 - 1;
        short8 afr[4][2];
        const short* wt = wt2 + tap * 4096;
#pragma unroll
        for (int m = 0; m < 4; m++)
#pragma unroll
            for (int ks = 0; ks < 2; ks++)
                afr[m][ks] = *(const short8*)(wt + (m * 16 + ln) * 64 + ks * 32 + g * 8);
#pragma unroll
        for (int nt = 0; nt < 7; nt++) {
            int prel = prel0 + nt * 16;
            int rrel = prel / 56;
            int xcol = prel - rrel * 56;
            int row_l = rrel + 1 + dy;
            int col_l = xcol + 1 + dx;
            int base = (row_l * 58 + col_l) * 64;
            int sw = (col_l & 7) << 3;
#pragma unroll
            for (int ks = 0; ks < 2; ks++) {
                short8 bfr = *(const short8*)(&lds[base + ((ks * 32 + g * 8) ^ sw)]);
#pragma unroll
                for (int m = 0; m < 4; m++) acc[m][nt] = MFMA16(afr[m][ks], bfr, acc[m][nt]);
            }
        }
    }
#pragma unroll
    for (int nt = 0; nt < 7; nt++) {
        int px = p0 + prel0 + nt * 16;
        float mv = mask[b * HW + px];
#pragma unroll
        for (int m = 0; m < 4; m++) {
            int oc = m * 16 + g * 4;
            float y0 = fmaxf(acc[m][nt][0] * sc[oc + 0] + sh[oc + 0], 0.f) * mv * vs[oc + 0];
            float y1 = fmaxf(acc[m][nt][1] * sc[oc + 1] + sh[oc + 1], 0.f) * mv * vs[oc + 1];
            float y2 = fmaxf(acc[m][nt][2] * sc[oc + 2] + sh[oc + 2], 0.f) * mv * vs[oc + 2];
            float y3 = fmaxf(acc[m][nt][3] * sc[oc + 3] + sh[oc + 3], 0.f) * mv * vs[oc + 3];
            uint2 u;
            u.x = (unsigned)f2bf(y0) | ((unsigned)f2bf(y1) << 16);
            u.y = (unsigned)f2bf(y2) | ((unsigned)f2bf(y3) << 16);
            *(uint2*)(out2h + ((size_t)(b * HW + px)) * 64 + m * 16 + g * 4) = u;
        }
    }
}

// ---------------- Kernel 7: conv3 1x1 (64->256) swapped MFMA, act-first + pinned x-prefetch ----------------
__global__ __launch_bounds__(256, 2) void k_conv3(const short* __restrict__ out2h,
                                                  const short* __restrict__ w3bf,
                                                  const float* __restrict__ g3, const float* __restrict__ b3,
                                                  const float* __restrict__ m3, const float* __restrict__ v3,
                                                  const float* __restrict__ mask,
                                                  const float* __restrict__ x,
                                                  float* __restrict__ out) {
    int b = blockIdx.y;
    int ocb = blockIdx.x / 28;          // 0..1
    int pxb = blockIdx.x % 28;          // 0..27
    int p0 = pxb * 112;
    int tid = threadIdx.x, w = tid >> 6, lane = tid & 63, g = lane >> 4, ln = lane & 15;
    int oc0 = ocb * 128 + w * 32;

    short8 wfr[2][2];
#pragma unroll
    for (int m = 0; m < 2; m++)
#pragma unroll
        for (int ks = 0; ks < 2; ks++)
            wfr[m][ks] = *(const short8*)(w3bf + ((oc0 + m * 16 + ln) * 64 + ks * 32 + g * 8));

    short8 act[7][2];
#pragma unroll
    for (int nt = 0; nt < 7; nt++) {
        size_t arow = ((size_t)(b * HW + p0 + nt * 16 + ln)) * 64;
#pragma unroll
        for (int ks = 0; ks < 2; ks++)
            act[nt][ks] = *(const short8*)(out2h + arow + ks * 32 + g * 8);
    }

    f32x4 xr[2][7];
#pragma unroll
    for (int nt = 0; nt < 7; nt++) {
        int px0 = p0 + nt * 16 + g * 4;
#pragma unroll
        for (int m = 0; m < 2; m++) {
            int oc = oc0 + m * 16 + ln;
            xr[m][nt] = *(const f32x4*)(x + ((size_t)(b * COUT + oc)) * HW + px0);
        }
    }
    __builtin_amdgcn_sched_barrier(0);

    f32x4 acc[2][7];
    f32x4 zz = {0.f, 0.f, 0.f, 0.f};
#pragma unroll
    for (int m = 0; m < 2; m++)
#pragma unroll
        for (int nt = 0; nt < 7; nt++) acc[m][nt] = zz;
#pragma unroll
    for (int nt = 0; nt < 7; nt++)
#pragma unroll
        for (int ks = 0; ks < 2; ks++)
#pragma unroll
            for (int m = 0; m < 2; m++)
                acc[m][nt] = MFMA16(act[nt][ks], wfr[m][ks], acc[m][nt]);

    float s_[2], h_[2];
#pragma unroll
    for (int m = 0; m < 2; m++) {
        int oc = oc0 + m * 16 + ln;
        float s = g3[oc] * rsqrtf(v3[oc] + EPS);
        s_[m] = s;
        h_[m] = b3[oc] - m3[oc] * s;
    }
#pragma unroll
    for (int nt = 0; nt < 7; nt++) {
        int px0 = p0 + nt * 16 + g * 4;
        f32x4 mv = *(const f32x4*)(mask + (size_t)b * HW + px0);
#pragma unroll
        for (int m = 0; m < 2; m++) {
            int oc = oc0 + m * 16 + ln;
            size_t idx = ((size_t)(b * COUT + oc)) * HW + px0;
            f32x4 o;
#pragma unroll
            for (int i = 0; i < 4; i++)
                o[i] = fmaxf(xr[m][nt][i] + (acc[m][nt][i] * s_[m] + h_[m]) * mv[i], 0.f);
            *(f32x4*)(out + idx) = o;
        }
    }
}

extern "C" void kernel_launch(void* const* d_in, const int* in_sizes, int n_in,
                              void* d_out, int out_size, void* d_ws, size_t ws_size,
                              hipStream_t stream) {
    const float* x       = (const float*)d_in[0];
    const float* conv1_w = (const float*)d_in[1];
    const float* bn1_g   = (const float*)d_in[2];
    const float* bn1_b   = (const float*)d_in[3];
    const float* bn1_m   = (const float*)d_in[4];
    const float* bn1_v   = (const float*)d_in[5];
    const float* conv2_w = (const float*)d_in[6];
    const float* bn2_g   = (const float*)d_in[7];
    const float* bn2_b   = (const float*)d_in[8];
    const float* bn2_m   = (const float*)d_in[9];
    const float* bn2_v   = (const float*)d_in[10];
    const float* conv3_w = (const float*)d_in[11];
    const float* bn3_g   = (const float*)d_in[12];
    const float* bn3_b   = (const float*)d_in[13];
    const float* bn3_m   = (const float*)d_in[14];
    const float* bn3_v   = (const float*)d_in[15];
    const float* fc_w    = (const float*)d_in[16];
    const float* fc_b    = (const float*)d_in[17];
    const float* mask_w  = (const float*)d_in[18];
    const float* mask_b  = (const float*)d_in[19];
    (void)mask_b;   // constant bias cancels in (sal >= kth)

    char* wsb = (char*)d_ws;
    size_t off = 0;
    double* pooled = (double*)(wsb + off); off += (size_t)BATCH * CIN * 8;        // 128 KB
    double* spart  = (double*)(wsb + off); off += (size_t)BATCH * 16 * HW * 8;    // 25.7 MB
    float* vector  = (float*)(wsb + off);  off += (size_t)BATCH * WIDTH * 4;
    float* mask    = (float*)(wsb + off);  off += (size_t)BATCH * HW * 4;
    float* mdil    = (float*)(wsb + off);  off += (size_t)BATCH * HW * 4;
    short* w1bf    = (short*)(wsb + off);  off += (size_t)WIDTH * CIN * 2;
    short* wt2     = (short*)(wsb + off);  off += (size_t)9 * WIDTH * WIDTH * 2;
    short* w3bf    = (short*)(wsb + off);  off += (size_t)COUT * WIDTH * 2;
    short* out1h   = (short*)(wsb + off);  off += (size_t)BATCH * HW * WIDTH * 2; // 25.7 MB
    short* out2h   = (short*)(wsb + off);  off += (size_t)BATCH * HW * WIDTH * 2; // 25.7 MB
    (void)ws_size; (void)in_sizes; (void)n_in; (void)out_size;

    k_prep<<<272, 256, 0, stream>>>(conv1_w, conv2_w, conv3_w, w1bf, wt2, w3bf);
    k_poolsal<<<dim3(16, BATCH), 256, 0, stream>>>(x, mask_w, pooled, spart);
    k_chan<<<BATCH, 64, 0, stream>>>(pooled, fc_w, fc_b, vector);
    k_spmask<<<BATCH, 256, 0, stream>>>(spart, mask, mdil);
    k_conv1<<<dim3(7, BATCH), 256, 0, stream>>>(x, w1bf, bn1_g, bn1_b, bn1_m, bn1_v, mdil, vector, out1h);
    k_conv2<<<dim3(7, BATCH), 256, 0, stream>>>(out1h, wt2, bn2_g, bn2_b, bn2_m, bn2_v, mask, vector, out2h);
    k_conv3<<<dim3(56, BATCH), 256, 0, stream>>>(out2h, w3bf, bn3_g, bn3_b, bn3_m, bn3_v, mask, x, (float*)d_out);
}

// Round 8
// 286.343 us; speedup vs baseline: 2.1736x; 1.1310x over previous
//
#include <hip/hip_runtime.h>
#include <math.h>

#define BATCH 64
#define CIN   256
#define HH    56
#define WW    56
#define HW    (HH*WW)      // 3136
#define WIDTH 64
#define COUT  256
#define K_CH  32
#define K_SP  1568
#define EPS   1e-5f

typedef short short8 __attribute__((ext_vector_type(8)));
typedef float f32x4 __attribute__((ext_vector_type(4)));

#define MFMA16(a, b, c) __builtin_amdgcn_mfma_f32_16x16x32_bf16((a), (b), (c), 0, 0, 0)

__device__ __forceinline__ unsigned short f2bf(float f) {
    unsigned u = __builtin_bit_cast(unsigned, f);
    u += 0x7fffu + ((u >> 16) & 1u);
    return (unsigned short)(u >> 16);
}

// ---------------- Kernel 0: weight prep (fp32 -> bf16, conv2 -> [tap][oc][c]) ----------------
__global__ __launch_bounds__(256) void k_prep(const float* __restrict__ w1,
                                              const float* __restrict__ w2,
                                              const float* __restrict__ w3,
                                              short* __restrict__ w1bf,
                                              short* __restrict__ wt2,
                                              short* __restrict__ w3bf) {
    int i = blockIdx.x * 256 + threadIdx.x;
    if (i < 16384) {
        w1bf[i] = (short)f2bf(w1[i]);
    } else if (i < 53248) {
        int j = i - 16384;              // [tap][oc][c]
        int tap = j >> 12, rem = j & 4095;
        int oc = rem >> 6, c = rem & 63;
        wt2[j] = (short)f2bf(w2[oc * 576 + c * 9 + tap]);
    } else if (i < 69632) {
        int j = i - 53248;
        w3bf[j] = (short)f2bf(w3[j]);
    }
}

// ---------------- Kernel 1: FUSED pool + spatial-saliency, single x pass ----------------
__global__ __launch_bounds__(256) void k_poolsal(const float* __restrict__ x,
                                                 const float* __restrict__ mask_w,
                                                 double* __restrict__ pooled,
                                                 double* __restrict__ spart) {
    int ct = blockIdx.x, b = blockIdx.y;
    int tid = threadIdx.x;
    double sp[13];
#pragma unroll
    for (int i = 0; i < 13; i++) sp[i] = 0.0;
    double pc[16];
#pragma unroll
    for (int c = 0; c < 16; c++) pc[c] = 0.0;

#pragma unroll
    for (int c = 0; c < 16; c++) {
        const float* xr = x + ((size_t)(b * CIN + ct * 16 + c)) * HW;
        double w = (double)mask_w[ct * 16 + c];
#pragma unroll
        for (int i = 0; i < 13; i++) {
            int px = i * 256 + tid;
            if (px < HW) {
                double v = (double)xr[px];
                sp[i] += v * w;
                pc[c] += v;
            }
        }
    }
    double* so = spart + ((size_t)(b * 16 + ct)) * HW;
#pragma unroll
    for (int i = 0; i < 13; i++) {
        int px = i * 256 + tid;
        if (px < HW) so[px] = sp[i];
    }
    __shared__ double pl[16][257];
#pragma unroll
    for (int c = 0; c < 16; c++) pl[c][tid] = pc[c];
    __syncthreads();
    for (int off = 128; off > 0; off >>= 1) {
        for (int k = tid; k < 16 * off; k += 256) {
            int c = k / off, j = k - c * off;
            pl[c][j] += pl[c][j + off];
        }
        __syncthreads();
    }
    if (tid < 16) pooled[b * CIN + ct * 16 + tid] = pl[tid][0] * (1.0 / (double)HW);
}

// ---------------- Kernel 3: channel saliency + top-K_CH mask + kept-index list ----------------
__global__ __launch_bounds__(64) void k_chan(const double* __restrict__ pooled,
                                             const float* __restrict__ fc_w,
                                             const float* __restrict__ fc_b,
                                             float* __restrict__ vector,
                                             int* __restrict__ kidx) {
    int b = blockIdx.x;
    int j = threadIdx.x;
    __shared__ double ps[CIN];
    for (int i = j; i < CIN; i += 64) ps[i] = pooled[b * CIN + i];
    __syncthreads();
    double acc = (double)fc_b[j];
    const float* wr = fc_w + j * CIN;
    for (int k = 0; k < CIN; k++) acc += ps[k] * (double)wr[k];
    double sal = 1.0 / (1.0 + exp(-acc));
    __shared__ double ss[WIDTH];
    __shared__ double kth;
    ss[j] = sal;
    __syncthreads();
    int cg = 0, ce = 0;
    for (int i = 0; i < WIDTH; i++) {
        cg += (ss[i] > sal);
        ce += (ss[i] == sal);
    }
    if (cg <= K_CH - 1 && cg + ce >= K_CH) kth = sal;
    __syncthreads();
    int kept = (sal >= kth) ? 1 : 0;
    vector[b * WIDTH + j] = (float)kept;
    // compact index (ascending channel order, deterministic)
    int pos = 0;
    for (int i = 0; i < j; i++) pos += (ss[i] >= kth) ? 1 : 0;
    if (kept && pos < K_CH) kidx[b * K_CH + pos] = j;
}

// ---------------- Kernel 3b: per-batch compacted weights for conv2 (9x32x32) and conv3 (256x32) ----------------
__global__ __launch_bounds__(256) void k_gather(const int* __restrict__ kidx,
                                                const short* __restrict__ wt2,
                                                const short* __restrict__ w3bf,
                                                short* __restrict__ wt2c,
                                                short* __restrict__ w3c) {
    int b = blockIdx.x, tid = threadIdx.x;
    __shared__ int ki[K_CH];
    if (tid < K_CH) ki[tid] = kidx[b * K_CH + tid];
    __syncthreads();
    // wt2c[b][tap][oc_c][c_c], 9*32*32 = 9216
    for (int i = tid; i < 9216; i += 256) {
        int tap = i >> 10, rem = i & 1023;
        int oc_c = rem >> 5, c_c = rem & 31;
        wt2c[(size_t)b * 9216 + i] = wt2[tap * 4096 + ki[oc_c] * 64 + ki[c_c]];
    }
    // w3c[b][oc][c_c], 256*32 = 8192
    for (int i = tid; i < 8192; i += 256) {
        int oc = i >> 5, c_c = i & 31;
        w3c[(size_t)b * 8192 + i] = w3bf[oc * 64 + ki[c_c]];
    }
}

// ---------------- Kernel 4: spatial kth via EXACT 64-bit radix-select + mask + 3x3 dilate ----------------
__global__ __launch_bounds__(256) void k_spmask(const double* __restrict__ spart,
                                                float* __restrict__ mask,
                                                float* __restrict__ mdil) {
    int b = blockIdx.x;
    int tid = threadIdx.x;
    __shared__ unsigned long long ks[HW];
    __shared__ float m[HW];
    __shared__ unsigned int hist[256];
    __shared__ unsigned int sc[256];
    __shared__ unsigned long long sh_prefix;
    __shared__ unsigned int sh_krem;

#pragma unroll
    for (int i = 0; i < 13; i++) {
        int px = i * 256 + tid;
        if (px < HW) {
            double s = 0.0;
#pragma unroll
            for (int t = 0; t < 16; t++) s += spart[((size_t)(b * 16 + t)) * HW + px];
            unsigned long long u = __builtin_bit_cast(unsigned long long, s);
            ks[px] = (u >> 63) ? ~u : (u | 0x8000000000000000ULL);
        }
    }
    if (tid == 0) { sh_prefix = 0ULL; sh_krem = K_SP; }
    __syncthreads();

    unsigned long long pmask = 0ULL;
    for (int pass = 0; pass < 8; pass++) {
        int shift = 56 - 8 * pass;
        hist[tid] = 0;
        __syncthreads();
        unsigned long long prefix = sh_prefix;
#pragma unroll
        for (int i = 0; i < 13; i++) {
            int px = i * 256 + tid;
            if (px < HW) {
                unsigned long long k = ks[px];
                if ((k & pmask) == prefix)
                    atomicAdd(&hist[(unsigned)((k >> shift) & 255ULL)], 1u);
            }
        }
        __syncthreads();
        sc[tid] = hist[255 - tid];
        __syncthreads();
        for (int off = 1; off < 256; off <<= 1) {
            unsigned v = sc[tid];
            unsigned a = (tid >= off) ? sc[tid - off] : 0u;
            __syncthreads();
            sc[tid] = v + a;
            __syncthreads();
        }
        unsigned krem = sh_krem;
        unsigned cum = sc[tid];
        unsigned cumHigher = (tid > 0) ? sc[tid - 1] : 0u;
        __syncthreads();
        if (cum >= krem && cumHigher < krem) {
            int d = 255 - tid;
            sh_krem = krem - cumHigher;
            sh_prefix = prefix | ((unsigned long long)d << shift);
        }
        pmask |= (0xFFULL << shift);
        __syncthreads();
    }
    unsigned long long kth = sh_prefix;

#pragma unroll
    for (int i = 0; i < 13; i++) {
        int px = i * 256 + tid;
        if (px < HW) {
            float mv = (ks[px] >= kth) ? 1.0f : 0.0f;
            m[px] = mv;
            mask[b * HW + px] = mv;
        }
    }
    __syncthreads();
    for (int p = tid; p < HW; p += 256) {
        int y = p / WW, xx = p % WW;
        float mx = 0.0f;
        for (int dy = -1; dy <= 1; dy++) {
            int yy = y + dy;
            if (yy < 0 || yy >= HH) continue;
            for (int dx = -1; dx <= 1; dx++) {
                int xc = xx + dx;
                if (xc < 0 || xc >= WW) continue;
                mx = fmaxf(mx, m[yy * WW + xc]);
            }
        }
        mdil[b * HW + p] = mx;
    }
}

// ---------------- Kernel 5: conv1 1x1 (256->32 kept) MFMA + bn1 + relu + mdil -> compact NHWC bf16 ----------------
// grid (7, BATCH), 256 thr. Only the 32 kept output channels are computed (vector=1 there).
__global__ __launch_bounds__(256, 2) void k_conv1(const float* __restrict__ x,
                                                  const short* __restrict__ w1bf,
                                                  const float* __restrict__ g1, const float* __restrict__ b1,
                                                  const float* __restrict__ m1, const float* __restrict__ v1,
                                                  const float* __restrict__ mdil,
                                                  const int* __restrict__ kidx,
                                                  short* __restrict__ out1c) {
    __shared__ short lds[448 * 64];   // 57344 B
    __shared__ float scc[32], shc[32];
    __shared__ int ki[32];
    int b = blockIdx.y, r0 = blockIdx.x * 8, p0 = r0 * 56;
    int tid = threadIdx.x, w = tid >> 6, lane = tid & 63, g = lane >> 4, ln = lane & 15;
    if (tid < 32) {
        int c = kidx[b * K_CH + tid];
        ki[tid] = c;
        float s = g1[c] * rsqrtf(v1[c] + EPS);
        scc[tid] = s; shc[tid] = b1[c] - m1[c] * s;
    }
    f32x4 acc[2][7];
    f32x4 zz = {0.f, 0.f, 0.f, 0.f};
#pragma unroll
    for (int m = 0; m < 2; m++)
#pragma unroll
        for (int nt = 0; nt < 7; nt++) acc[m][nt] = zz;

    int pxl0 = w * 112 + ln;
    int swl = (pxl0 & 7) << 3;

    for (int kc = 0; kc < 4; kc++) {
        __syncthreads();
        const float* xsrc = x + ((size_t)(b * 256 + kc * 64)) * HW + p0;
        {
            int c = 0, px = tid;
            for (int i = 0; i < 112; i++) {
                float f = xsrc[(size_t)c * HW + px];
                lds[px * 64 + (c ^ ((px & 7) << 3))] = (short)f2bf(f);
                px += 256;
                if (px >= 448) { px -= 448; c++; }
            }
        }
        __syncthreads();
        short8 afr[2][2];
#pragma unroll
        for (int m = 0; m < 2; m++)
#pragma unroll
            for (int ks = 0; ks < 2; ks++)
                afr[m][ks] = *(const short8*)(w1bf + (ki[m * 16 + ln] * 256 + kc * 64 + ks * 32 + g * 8));
#pragma unroll
        for (int nt = 0; nt < 7; nt++) {
#pragma unroll
            for (int ks = 0; ks < 2; ks++) {
                short8 bfr = *(const short8*)(&lds[(pxl0 + nt * 16) * 64 + (((ks * 32 + g * 8)) ^ swl)]);
#pragma unroll
                for (int m = 0; m < 2; m++) acc[m][nt] = MFMA16(afr[m][ks], bfr, acc[m][nt]);
            }
        }
    }
#pragma unroll
    for (int nt = 0; nt < 7; nt++) {
        int px = p0 + pxl0 + nt * 16;
        float md = mdil[b * HW + px];
#pragma unroll
        for (int m = 0; m < 2; m++) {
            int oc = m * 16 + g * 4;
            float y0 = fmaxf(acc[m][nt][0] * scc[oc + 0] + shc[oc + 0], 0.f) * md;
            float y1 = fmaxf(acc[m][nt][1] * scc[oc + 1] + shc[oc + 1], 0.f) * md;
            float y2 = fmaxf(acc[m][nt][2] * scc[oc + 2] + shc[oc + 2], 0.f) * md;
            float y3 = fmaxf(acc[m][nt][3] * scc[oc + 3] + shc[oc + 3], 0.f) * md;
            uint2 u;
            u.x = (unsigned)f2bf(y0) | ((unsigned)f2bf(y1) << 16);
            u.y = (unsigned)f2bf(y2) | ((unsigned)f2bf(y3) << 16);
            *(uint2*)(out1c + ((size_t)(b * HW + px)) * 32 + oc) = u;
        }
    }
}

// ---------------- Kernel 6: conv2 3x3 (32->32 kept) MFMA shift-GEMM + bn2 + relu + mask ----------------
// LDS halo tile [10][58][32] bf16 = 37120 B; per-batch compacted weights wt2c.
__global__ __launch_bounds__(256, 2) void k_conv2(const short* __restrict__ out1c,
                                                  const short* __restrict__ wt2c,
                                                  const float* __restrict__ g2, const float* __restrict__ b2,
                                                  const float* __restrict__ m2, const float* __restrict__ v2,
                                                  const float* __restrict__ mask,
                                                  const int* __restrict__ kidx,
                                                  short* __restrict__ out2c) {
    __shared__ short lds[10 * 58 * 32];   // 37120 B
    __shared__ float scc[32], shc[32];
    int b = blockIdx.y, r0 = blockIdx.x * 8, p0 = r0 * 56;
    int tid = threadIdx.x, w = tid >> 6, lane = tid & 63, g = lane >> 4, ln = lane & 15;
    if (tid < 32) {
        int c = kidx[b * K_CH + tid];
        float s = g2[c] * rsqrtf(v2[c] + EPS);
        scc[tid] = s; shc[tid] = b2[c] - m2[c] * s;
    }
    short8 z8 = {0, 0, 0, 0, 0, 0, 0, 0};
    for (int i = tid; i < 2320; i += 256) {      // 10*58*4 chunks of 8 shorts
        int cblk = i & 3;
        int colr = i >> 2;
        int col = colr % 58, ri = colr / 58;
        int gr = r0 - 1 + ri, gc = col - 1;
        short8 v8 = z8;
        if (gr >= 0 && gr < HH && gc >= 0 && gc < WW)
            v8 = *(const short8*)(out1c + ((size_t)(b * HW + gr * WW + gc)) * 32 + cblk * 8);
        *(short8*)(&lds[(ri * 58 + col) * 32 + ((cblk * 8) ^ ((col & 3) << 3))]) = v8;
    }
    __syncthreads();

    f32x4 acc[2][7];
    f32x4 zz = {0.f, 0.f, 0.f, 0.f};
#pragma unroll
    for (int m = 0; m < 2; m++)
#pragma unroll
        for (int nt = 0; nt < 7; nt++) acc[m][nt] = zz;

    const short* wtb = wt2c + (size_t)b * 9216;
    int prel0 = w * 112 + ln;
    for (int tap = 0; tap < 9; tap++) {
        int dy = tap / 3 - 1;
        int dx = tap - (tap / 3) * 3 - 1;
        short8 afr[2];
#pragma unroll
        for (int m = 0; m < 2; m++)
            afr[m] = *(const short8*)(wtb + tap * 1024 + (m * 16 + ln) * 32 + g * 8);
#pragma unroll
        for (int nt = 0; nt < 7; nt++) {
            int prel = prel0 + nt * 16;
            int rrel = prel / 56;
            int xcol = prel - rrel * 56;
            int row_l = rrel + 1 + dy;
            int col_l = xcol + 1 + dx;
            short8 bfr = *(const short8*)(&lds[(row_l * 58 + col_l) * 32 + ((g * 8) ^ ((col_l & 3) << 3))]);
#pragma unroll
            for (int m = 0; m < 2; m++) acc[m][nt] = MFMA16(afr[m], bfr, acc[m][nt]);
        }
    }
#pragma unroll
    for (int nt = 0; nt < 7; nt++) {
        int px = p0 + prel0 + nt * 16;
        float mv = mask[b * HW + px];
#pragma unroll
        for (int m = 0; m < 2; m++) {
            int oc = m * 16 + g * 4;
            float y0 = fmaxf(acc[m][nt][0] * scc[oc + 0] + shc[oc + 0], 0.f) * mv;
            float y1 = fmaxf(acc[m][nt][1] * scc[oc + 1] + shc[oc + 1], 0.f) * mv;
            float y2 = fmaxf(acc[m][nt][2] * scc[oc + 2] + shc[oc + 2], 0.f) * mv;
            float y3 = fmaxf(acc[m][nt][3] * scc[oc + 3] + shc[oc + 3], 0.f) * mv;
            uint2 u;
            u.x = (unsigned)f2bf(y0) | ((unsigned)f2bf(y1) << 16);
            u.y = (unsigned)f2bf(y2) | ((unsigned)f2bf(y3) << 16);
            *(uint2*)(out2c + ((size_t)(b * HW + px)) * 32 + oc) = u;
        }
    }
}

// ---------------- Kernel 7: conv3 1x1 (32 kept ->256) swapped MFMA, act-first + pinned x-prefetch ----------------
__global__ __launch_bounds__(256, 2) void k_conv3(const short* __restrict__ out2c,
                                                  const short* __restrict__ w3c,
                                                  const float* __restrict__ g3, const float* __restrict__ b3,
                                                  const float* __restrict__ m3, const float* __restrict__ v3,
                                                  const float* __restrict__ mask,
                                                  const float* __restrict__ x,
                                                  float* __restrict__ out) {
    int b = blockIdx.y;
    int ocb = blockIdx.x / 28;          // 0..1
    int pxb = blockIdx.x % 28;          // 0..27
    int p0 = pxb * 112;
    int tid = threadIdx.x, w = tid >> 6, lane = tid & 63, g = lane >> 4, ln = lane & 15;
    int oc0 = ocb * 128 + w * 32;

    const short* w3b = w3c + (size_t)b * 8192;
    short8 wfr[2];
#pragma unroll
    for (int m = 0; m < 2; m++)
        wfr[m] = *(const short8*)(w3b + (oc0 + m * 16 + ln) * 32 + g * 8);

    short8 act[7];
#pragma unroll
    for (int nt = 0; nt < 7; nt++)
        act[nt] = *(const short8*)(out2c + ((size_t)(b * HW + p0 + nt * 16 + ln)) * 32 + g * 8);

    f32x4 xr[2][7];
#pragma unroll
    for (int nt = 0; nt < 7; nt++) {
        int px0 = p0 + nt * 16 + g * 4;
#pragma unroll
        for (int m = 0; m < 2; m++) {
            int oc = oc0 + m * 16 + ln;
            xr[m][nt] = *(const f32x4*)(x + ((size_t)(b * COUT + oc)) * HW + px0);
        }
    }
    __builtin_amdgcn_sched_barrier(0);

    f32x4 acc[2][7];
    f32x4 zz = {0.f, 0.f, 0.f, 0.f};
#pragma unroll
    for (int m = 0; m < 2; m++)
#pragma unroll
        for (int nt = 0; nt < 7; nt++) acc[m][nt] = zz;
#pragma unroll
    for (int nt = 0; nt < 7; nt++)
#pragma unroll
        for (int m = 0; m < 2; m++)
            acc[m][nt] = MFMA16(act[nt], wfr[m], acc[m][nt]);

    float s_[2], h_[2];
#pragma unroll
    for (int m = 0; m < 2; m++) {
        int oc = oc0 + m * 16 + ln;
        float s = g3[oc] * rsqrtf(v3[oc] + EPS);
        s_[m] = s;
        h_[m] = b3[oc] - m3[oc] * s;
    }
#pragma unroll
    for (int nt = 0; nt < 7; nt++) {
        int px0 = p0 + nt * 16 + g * 4;
        f32x4 mv = *(const f32x4*)(mask + (size_t)b * HW + px0);
#pragma unroll
        for (int m = 0; m < 2; m++) {
            int oc = oc0 + m * 16 + ln;
            size_t idx = ((size_t)(b * COUT + oc)) * HW + px0;
            f32x4 o;
#pragma unroll
            for (int i = 0; i < 4; i++)
                o[i] = fmaxf(xr[m][nt][i] + (acc[m][nt][i] * s_[m] + h_[m]) * mv[i], 0.f);
            *(f32x4*)(out + idx) = o;
        }
    }
}

extern "C" void kernel_launch(void* const* d_in, const int* in_sizes, int n_in,
                              void* d_out, int out_size, void* d_ws, size_t ws_size,
                              hipStream_t stream) {
    const float* x       = (const float*)d_in[0];
    const float* conv1_w = (const float*)d_in[1];
    const float* bn1_g   = (const float*)d_in[2];
    const float* bn1_b   = (const float*)d_in[3];
    const float* bn1_m   = (const float*)d_in[4];
    const float* bn1_v   = (const float*)d_in[5];
    const float* conv2_w = (const float*)d_in[6];
    const float* bn2_g   = (const float*)d_in[7];
    const float* bn2_b   = (const float*)d_in[8];
    const float* bn2_m   = (const float*)d_in[9];
    const float* bn2_v   = (const float*)d_in[10];
    const float* conv3_w = (const float*)d_in[11];
    const float* bn3_g   = (const float*)d_in[12];
    const float* bn3_b   = (const float*)d_in[13];
    const float* bn3_m   = (const float*)d_in[14];
    const float* bn3_v   = (const float*)d_in[15];
    const float* fc_w    = (const float*)d_in[16];
    const float* fc_b    = (const float*)d_in[17];
    const float* mask_w  = (const float*)d_in[18];
    const float* mask_b  = (const float*)d_in[19];
    (void)mask_b;   // constant bias cancels in (sal >= kth)

    char* wsb = (char*)d_ws;
    size_t off = 0;
    double* pooled = (double*)(wsb + off); off += (size_t)BATCH * CIN * 8;        // 128 KB
    double* spart  = (double*)(wsb + off); off += (size_t)BATCH * 16 * HW * 8;    // 25.7 MB
    float* vector  = (float*)(wsb + off);  off += (size_t)BATCH * WIDTH * 4;
    float* mask    = (float*)(wsb + off);  off += (size_t)BATCH * HW * 4;
    float* mdil    = (float*)(wsb + off);  off += (size_t)BATCH * HW * 4;
    int*   kidx    = (int*)(wsb + off);    off += (size_t)BATCH * K_CH * 4;
    short* w1bf    = (short*)(wsb + off);  off += (size_t)WIDTH * CIN * 2;
    short* wt2     = (short*)(wsb + off);  off += (size_t)9 * WIDTH * WIDTH * 2;
    short* w3bf    = (short*)(wsb + off);  off += (size_t)COUT * WIDTH * 2;
    short* wt2c    = (short*)(wsb + off);  off += (size_t)BATCH * 9216 * 2;       // 1.18 MB
    short* w3c     = (short*)(wsb + off);  off += (size_t)BATCH * 8192 * 2;       // 1.05 MB
    short* out1c   = (short*)(wsb + off);  off += (size_t)BATCH * HW * 32 * 2;    // 12.8 MB
    short* out2c   = (short*)(wsb + off);  off += (size_t)BATCH * HW * 32 * 2;    // 12.8 MB
    (void)ws_size; (void)in_sizes; (void)n_in; (void)out_size; (void)vector;

    k_prep<<<272, 256, 0, stream>>>(conv1_w, conv2_w, conv3_w, w1bf, wt2, w3bf);
    k_poolsal<<<dim3(16, BATCH), 256, 0, stream>>>(x, mask_w, pooled, spart);
    k_chan<<<BATCH, 64, 0, stream>>>(pooled, fc_w, fc_b, vector, kidx);
    k_gather<<<BATCH, 256, 0, stream>>>(kidx, wt2, w3bf, wt2c, w3c);
    k_spmask<<<BATCH, 256, 0, stream>>>(spart, mask, mdil);
    k_conv1<<<dim3(7, BATCH), 256, 0, stream>>>(x, w1bf, bn1_g, bn1_b, bn1_m, bn1_v, mdil, kidx, out1c);
    k_conv2<<<dim3(7, BATCH), 256, 0, stream>>>(out1c, wt2c, bn2_g, bn2_b, bn2_m, bn2_v, mask, kidx, out2c);
    k_conv3<<<dim3(56, BATCH), 256, 0, stream>>>(out2c, w3c, bn3_g, bn3_b, bn3_m, bn3_v, mask, x, (float*)d_out);
}